// Round 1
// baseline (7029.467 us; speedup 1.0000x reference)
//
#include <hip/hip_runtime.h>

#define Q 16
#define EPS 1e-8f
#define DEPTH 5

// Kernel A: per edge e -> t = log(cav[e]@C + eps); temp2[e]=t; marg[dst[e]] += t (atomic).
__global__ __launch_bounds__(256) void edge_forward(
    const float* __restrict__ cav, const float* __restrict__ C,
    const int* __restrict__ edge_dst, float* __restrict__ temp2,
    float* __restrict__ marg, int E)
{
    __shared__ float Cs[Q * Q];
    Cs[threadIdx.x] = C[threadIdx.x];   // blockDim == 256 == Q*Q
    __syncthreads();

    int e = blockIdx.x * 256 + threadIdx.x;
    if (e >= E) return;

    const float4* rp = (const float4*)(cav + (size_t)e * Q);
    float4 a0 = rp[0], a1 = rp[1], a2 = rp[2], a3 = rp[3];
    float r[Q] = {a0.x, a0.y, a0.z, a0.w, a1.x, a1.y, a1.z, a1.w,
                  a2.x, a2.y, a2.z, a2.w, a3.x, a3.y, a3.z, a3.w};

    float t[Q];
#pragma unroll
    for (int q = 0; q < Q; ++q) {
        float acc = 0.f;
#pragma unroll
        for (int k = 0; k < Q; ++k) acc += r[k] * Cs[k * Q + q];  // broadcast LDS reads
        t[q] = __logf(acc + EPS);
    }

    float4* tp = (float4*)(temp2 + (size_t)e * Q);
    tp[0] = make_float4(t[0],  t[1],  t[2],  t[3]);
    tp[1] = make_float4(t[4],  t[5],  t[6],  t[7]);
    tp[2] = make_float4(t[8],  t[9],  t[10], t[11]);
    tp[3] = make_float4(t[12], t[13], t[14], t[15]);

    float* m = marg + (size_t)edge_dst[e] * Q;
#pragma unroll
    for (int q = 0; q < Q; ++q) atomicAdd(m + q, t[q]);
}

// Kernel B: per edge e -> cav[e] = softmax(marg[a1_src[e]] - temp2[indice_ij[e]]).
__global__ __launch_bounds__(256) void edge_update(
    const float* __restrict__ marg, const float* __restrict__ temp2,
    const int* __restrict__ a1_src, const int* __restrict__ indice_ij,
    float* __restrict__ cav_out, int E)
{
    int e = blockIdx.x * 256 + threadIdx.x;
    if (e >= E) return;

    const float4* mp = (const float4*)(marg  + (size_t)a1_src[e]    * Q);
    const float4* tp = (const float4*)(temp2 + (size_t)indice_ij[e] * Q);
    float4 m0 = mp[0], m1 = mp[1], m2 = mp[2], m3 = mp[3];
    float4 t0 = tp[0], t1 = tp[1], t2 = tp[2], t3 = tp[3];

    float x[Q] = {m0.x - t0.x, m0.y - t0.y, m0.z - t0.z, m0.w - t0.w,
                  m1.x - t1.x, m1.y - t1.y, m1.z - t1.z, m1.w - t1.w,
                  m2.x - t2.x, m2.y - t2.y, m2.z - t2.z, m2.w - t2.w,
                  m3.x - t3.x, m3.y - t3.y, m3.z - t3.z, m3.w - t3.w};

    float mx = x[0];
#pragma unroll
    for (int q = 1; q < Q; ++q) mx = fmaxf(mx, x[q]);
    float s = 0.f;
#pragma unroll
    for (int q = 0; q < Q; ++q) { x[q] = __expf(x[q] - mx); s += x[q]; }
    float inv = 1.f / s;

    float4* op = (float4*)(cav_out + (size_t)e * Q);
    op[0] = make_float4(x[0]  * inv, x[1]  * inv, x[2]  * inv, x[3]  * inv);
    op[1] = make_float4(x[4]  * inv, x[5]  * inv, x[6]  * inv, x[7]  * inv);
    op[2] = make_float4(x[8]  * inv, x[9]  * inv, x[10] * inv, x[11] * inv);
    op[3] = make_float4(x[12] * inv, x[13] * inv, x[14] * inv, x[15] * inv);
}

// Final: per node log_softmax.
__global__ __launch_bounds__(256) void node_out(
    const float* __restrict__ marg, float* __restrict__ out, int N)
{
    int i = blockIdx.x * 256 + threadIdx.x;
    if (i >= N) return;

    const float4* mp = (const float4*)(marg + (size_t)i * Q);
    float4 m0 = mp[0], m1 = mp[1], m2 = mp[2], m3 = mp[3];
    float x[Q] = {m0.x, m0.y, m0.z, m0.w, m1.x, m1.y, m1.z, m1.w,
                  m2.x, m2.y, m2.z, m2.w, m3.x, m3.y, m3.z, m3.w};

    float mx = x[0];
#pragma unroll
    for (int q = 1; q < Q; ++q) mx = fmaxf(mx, x[q]);
    float s = 0.f;
#pragma unroll
    for (int q = 0; q < Q; ++q) s += __expf(x[q] - mx);
    float lse = mx + __logf(s);

    float4* op = (float4*)(out + (size_t)i * Q);
    op[0] = make_float4(x[0]  - lse, x[1]  - lse, x[2]  - lse, x[3]  - lse);
    op[1] = make_float4(x[4]  - lse, x[5]  - lse, x[6]  - lse, x[7]  - lse);
    op[2] = make_float4(x[8]  - lse, x[9]  - lse, x[10] - lse, x[11] - lse);
    op[3] = make_float4(x[12] - lse, x[13] - lse, x[14] - lse, x[15] - lse);
}

extern "C" void kernel_launch(void* const* d_in, const int* in_sizes, int n_in,
                              void* d_out, int out_size, void* d_ws, size_t ws_size,
                              hipStream_t stream) {
    // inputs: 0 marg_i (dead for DEPTH>=1), 1 cav_ij, 2 C, 3 field_i,
    //         4 edge_dst, 5 a1_src, 6 indice_ij
    const float* cav_in   = (const float*)d_in[1];
    const float* C        = (const float*)d_in[2];
    const float* field_i  = (const float*)d_in[3];
    const int*   edge_dst = (const int*)d_in[4];
    const int*   a1_src   = (const int*)d_in[5];
    const int*   indice   = (const int*)d_in[6];
    float* out = (float*)d_out;

    const int E = in_sizes[4];
    const int N = in_sizes[0] / Q;

    char* ws = (char*)d_ws;
    const size_t edge_bytes = (size_t)E * Q * sizeof(float);
    float* temp2 = (float*)ws;                    // [E,Q]
    float* cavb  = (float*)(ws + edge_bytes);     // [E,Q] ping buffer
    float* marg  = (float*)(ws + 2 * edge_bytes); // [N,Q]

    const int eb = 256;
    const int eg = (E + eb - 1) / eb;
    const int ng = (N + eb - 1) / eb;

    for (int it = 0; it < DEPTH; ++it) {
        // marg = field_i (accumulation base)
        hipMemcpyAsync(marg, field_i, (size_t)N * Q * sizeof(float),
                       hipMemcpyDeviceToDevice, stream);
        edge_forward<<<eg, eb, 0, stream>>>(it == 0 ? cav_in : cavb, C,
                                            edge_dst, temp2, marg, E);
        if (it != DEPTH - 1)  // final round's cav is dead
            edge_update<<<eg, eb, 0, stream>>>(marg, temp2, a1_src, indice, cavb, E);
    }
    node_out<<<ng, eb, 0, stream>>>(marg, out, N);
}

// Round 2
// 1163.738 us; speedup vs baseline: 6.0404x; 6.0404x over previous
//
#include <hip/hip_runtime.h>

#define Q 16
#define EPS 1e-8f
#define DEPTH 5

// ---------- one-time CSR build (edge_dst is constant across rounds) ----------

__global__ __launch_bounds__(256) void hist_kernel(
    const int* __restrict__ dst, int* __restrict__ count, int E)
{
    int e = blockIdx.x * 256 + threadIdx.x;
    if (e < E) atomicAdd(&count[dst[e]], 1);
}

// single-block exclusive scan of count[0..N) -> start[0..N]
__global__ __launch_bounds__(1024) void scan_kernel(
    const int* __restrict__ count, int* __restrict__ start, int N)
{
    __shared__ int part[1024];
    const int t = threadIdx.x;
    const int chunk = (N + 1023) / 1024;
    const int lo = t * chunk;
    const int hi = min(lo + chunk, N);

    int s = 0;
    for (int i = lo; i < hi; ++i) s += count[i];
    part[t] = s;
    __syncthreads();

    // Hillis-Steele inclusive scan over the 1024 partials
    for (int off = 1; off < 1024; off <<= 1) {
        int u = (t >= off) ? part[t - off] : 0;
        __syncthreads();
        part[t] += u;
        __syncthreads();
    }

    int base = part[t] - s;  // exclusive prefix of this chunk
    int run = base;
    for (int i = lo; i < hi; ++i) { start[i] = run; run += count[i]; }
    if (t == 1023) start[N] = part[1023];
}

__global__ __launch_bounds__(256) void scatter_kernel(
    const int* __restrict__ dst, int* __restrict__ cursor,
    int* __restrict__ perm, int E)
{
    int e = blockIdx.x * 256 + threadIdx.x;
    if (e < E) {
        int p = atomicAdd(&cursor[dst[e]], 1);
        perm[p] = e;
    }
}

// ---------- per-round kernels ----------

// per edge e: temp2[e] = log(cav[e]@C + eps)   (no atomics)
__global__ __launch_bounds__(256) void edge_forward(
    const float* __restrict__ cav, const float* __restrict__ C,
    float* __restrict__ temp2, int E)
{
    __shared__ float Cs[Q * Q];
    Cs[threadIdx.x] = C[threadIdx.x];   // blockDim == 256 == Q*Q
    __syncthreads();

    int e = blockIdx.x * 256 + threadIdx.x;
    if (e >= E) return;

    const float4* rp = (const float4*)(cav + (size_t)e * Q);
    float4 a0 = rp[0], a1 = rp[1], a2 = rp[2], a3 = rp[3];
    float r[Q] = {a0.x, a0.y, a0.z, a0.w, a1.x, a1.y, a1.z, a1.w,
                  a2.x, a2.y, a2.z, a2.w, a3.x, a3.y, a3.z, a3.w};

    float t[Q];
#pragma unroll
    for (int q = 0; q < Q; ++q) {
        float acc = 0.f;
#pragma unroll
        for (int k = 0; k < Q; ++k) acc += r[k] * Cs[k * Q + q];
        t[q] = __logf(acc + EPS);
    }

    float4* tp = (float4*)(temp2 + (size_t)e * Q);
    tp[0] = make_float4(t[0],  t[1],  t[2],  t[3]);
    tp[1] = make_float4(t[4],  t[5],  t[6],  t[7]);
    tp[2] = make_float4(t[8],  t[9],  t[10], t[11]);
    tp[3] = make_float4(t[12], t[13], t[14], t[15]);
}

// one wave per node: marg[i] = field[i] + sum over edges of temp2[perm[j]]
// quarter-wave (16 lanes) per edge row -> contiguous 64B reads
__global__ __launch_bounds__(256) void node_reduce(
    const float* __restrict__ temp2, const int* __restrict__ perm,
    const int* __restrict__ start, const float* __restrict__ field,
    float* __restrict__ marg, int N)
{
    int wave = threadIdx.x >> 6;
    int node = blockIdx.x * 4 + wave;
    if (node >= N) return;
    int lane = threadIdx.x & 63;
    int sub = lane >> 4;      // 0..3
    int q = lane & 15;

    int lo = start[node], hi = start[node + 1];
    float acc = 0.f;
    for (int j = lo + sub; j < hi; j += 4) {
        int e = perm[j];
        acc += temp2[(size_t)e * Q + q];
    }
    acc += __shfl_xor(acc, 16, 64);
    acc += __shfl_xor(acc, 32, 64);
    if (lane < 16)
        marg[(size_t)node * Q + q] = acc + field[(size_t)node * Q + q];
}

// per edge e: cav[e] = softmax(marg[a1_src[e]] - temp2[indice_ij[e]])
__global__ __launch_bounds__(256) void edge_update(
    const float* __restrict__ marg, const float* __restrict__ temp2,
    const int* __restrict__ a1_src, const int* __restrict__ indice_ij,
    float* __restrict__ cav_out, int E)
{
    int e = blockIdx.x * 256 + threadIdx.x;
    if (e >= E) return;

    const float4* mp = (const float4*)(marg  + (size_t)a1_src[e]    * Q);
    const float4* tp = (const float4*)(temp2 + (size_t)indice_ij[e] * Q);
    float4 m0 = mp[0], m1 = mp[1], m2 = mp[2], m3 = mp[3];
    float4 t0 = tp[0], t1 = tp[1], t2 = tp[2], t3 = tp[3];

    float x[Q] = {m0.x - t0.x, m0.y - t0.y, m0.z - t0.z, m0.w - t0.w,
                  m1.x - t1.x, m1.y - t1.y, m1.z - t1.z, m1.w - t1.w,
                  m2.x - t2.x, m2.y - t2.y, m2.z - t2.z, m2.w - t2.w,
                  m3.x - t3.x, m3.y - t3.y, m3.z - t3.z, m3.w - t3.w};

    float mx = x[0];
#pragma unroll
    for (int q = 1; q < Q; ++q) mx = fmaxf(mx, x[q]);
    float s = 0.f;
#pragma unroll
    for (int q = 0; q < Q; ++q) { x[q] = __expf(x[q] - mx); s += x[q]; }
    float inv = 1.f / s;

    float4* op = (float4*)(cav_out + (size_t)e * Q);
    op[0] = make_float4(x[0]  * inv, x[1]  * inv, x[2]  * inv, x[3]  * inv);
    op[1] = make_float4(x[4]  * inv, x[5]  * inv, x[6]  * inv, x[7]  * inv);
    op[2] = make_float4(x[8]  * inv, x[9]  * inv, x[10] * inv, x[11] * inv);
    op[3] = make_float4(x[12] * inv, x[13] * inv, x[14] * inv, x[15] * inv);
}

// final: per node log_softmax
__global__ __launch_bounds__(256) void node_out(
    const float* __restrict__ marg, float* __restrict__ out, int N)
{
    int i = blockIdx.x * 256 + threadIdx.x;
    if (i >= N) return;

    const float4* mp = (const float4*)(marg + (size_t)i * Q);
    float4 m0 = mp[0], m1 = mp[1], m2 = mp[2], m3 = mp[3];
    float x[Q] = {m0.x, m0.y, m0.z, m0.w, m1.x, m1.y, m1.z, m1.w,
                  m2.x, m2.y, m2.z, m2.w, m3.x, m3.y, m3.z, m3.w};

    float mx = x[0];
#pragma unroll
    for (int q = 1; q < Q; ++q) mx = fmaxf(mx, x[q]);
    float s = 0.f;
#pragma unroll
    for (int q = 0; q < Q; ++q) s += __expf(x[q] - mx);
    float lse = mx + __logf(s);

    float4* op = (float4*)(out + (size_t)i * Q);
    op[0] = make_float4(x[0]  - lse, x[1]  - lse, x[2]  - lse, x[3]  - lse);
    op[1] = make_float4(x[4]  - lse, x[5]  - lse, x[6]  - lse, x[7]  - lse);
    op[2] = make_float4(x[8]  - lse, x[9]  - lse, x[10] - lse, x[11] - lse);
    op[3] = make_float4(x[12] - lse, x[13] - lse, x[14] - lse, x[15] - lse);
}

extern "C" void kernel_launch(void* const* d_in, const int* in_sizes, int n_in,
                              void* d_out, int out_size, void* d_ws, size_t ws_size,
                              hipStream_t stream) {
    // inputs: 0 marg_i (dead), 1 cav_ij, 2 C, 3 field_i, 4 edge_dst, 5 a1_src, 6 indice_ij
    const float* cav_in   = (const float*)d_in[1];
    const float* C        = (const float*)d_in[2];
    const float* field_i  = (const float*)d_in[3];
    const int*   edge_dst = (const int*)d_in[4];
    const int*   a1_src   = (const int*)d_in[5];
    const int*   indice   = (const int*)d_in[6];
    float* out = (float*)d_out;

    const int E = in_sizes[4];
    const int N = in_sizes[0] / Q;

    char* ws = (char*)d_ws;
    const size_t edge_bytes = (size_t)E * Q * sizeof(float);
    const size_t node_bytes = (size_t)N * Q * sizeof(float);
    float* temp2 = (float*)ws;                                   // [E,Q]
    float* cavb  = (float*)(ws + edge_bytes);                    // [E,Q]
    float* marg  = (float*)(ws + 2 * edge_bytes);                // [N,Q]
    char*  p     = ws + 2 * edge_bytes + node_bytes;
    int* perm   = (int*)p;                 p += (size_t)E * 4;   // [E]
    int* count  = (int*)p;                 p += (size_t)N * 4;   // [N]
    int* start  = (int*)p;                 p += (size_t)(N + 1) * 4; // [N+1]
    int* cursor = (int*)p;                                        // [N]

    const int eb = 256;
    const int eg = (E + eb - 1) / eb;
    const int ng = (N + eb - 1) / eb;
    const int rg = (N + 3) / 4;  // node_reduce: 4 waves/block, 1 node/wave

    // ---- one-time CSR build (ws is re-poisoned each call, so rebuild) ----
    hipMemsetAsync(count, 0, (size_t)N * 4, stream);
    hist_kernel<<<eg, eb, 0, stream>>>(edge_dst, count, E);
    scan_kernel<<<1, 1024, 0, stream>>>(count, start, N);
    hipMemcpyAsync(cursor, start, (size_t)N * 4, hipMemcpyDeviceToDevice, stream);
    scatter_kernel<<<eg, eb, 0, stream>>>(edge_dst, cursor, perm, E);

    // ---- DEPTH rounds ----
    for (int it = 0; it < DEPTH; ++it) {
        edge_forward<<<eg, eb, 0, stream>>>(it == 0 ? cav_in : cavb, C, temp2, E);
        node_reduce<<<rg, eb, 0, stream>>>(temp2, perm, start, field_i, marg, N);
        if (it != DEPTH - 1)  // final round's cav is dead
            edge_update<<<eg, eb, 0, stream>>>(marg, temp2, a1_src, indice, cavb, E);
    }
    node_out<<<ng, eb, 0, stream>>>(marg, out, N);
}

// Round 3
// 980.264 us; speedup vs baseline: 7.1710x; 1.1872x over previous
//
#include <hip/hip_runtime.h>

#define Q 16
#define EPS 1e-8f
#define DEPTH 5

// ---------- one-time CSR build (edge_dst is constant across rounds) ----------

__global__ __launch_bounds__(256) void hist_kernel(
    const int* __restrict__ dst, int* __restrict__ count, int E)
{
    int e = blockIdx.x * 256 + threadIdx.x;
    if (e < E) atomicAdd(&count[dst[e]], 1);
}

// single-block exclusive scan of count[0..N) -> start[0..N]
__global__ __launch_bounds__(1024) void scan_kernel(
    const int* __restrict__ count, int* __restrict__ start, int N)
{
    __shared__ int part[1024];
    const int t = threadIdx.x;
    const int chunk = (N + 1023) / 1024;
    const int lo = t * chunk;
    const int hi = min(lo + chunk, N);

    int s = 0;
    for (int i = lo; i < hi; ++i) s += count[i];
    part[t] = s;
    __syncthreads();

    for (int off = 1; off < 1024; off <<= 1) {
        int u = (t >= off) ? part[t - off] : 0;
        __syncthreads();
        part[t] += u;
        __syncthreads();
    }

    int base = part[t] - s;
    int run = base;
    for (int i = lo; i < hi; ++i) { start[i] = run; run += count[i]; }
    if (t == 1023) start[N] = part[1023];
}

__global__ __launch_bounds__(256) void scatter_kernel(
    const int* __restrict__ dst, int* __restrict__ cursor,
    int* __restrict__ perm, int E)
{
    int e = blockIdx.x * 256 + threadIdx.x;
    if (e < E) {
        int p = atomicAdd(&cursor[dst[e]], 1);
        perm[p] = e;
    }
}

// ---------- per-round kernels ----------

// Round 1 only: temp2[e] = log(cav_in[e]@C + eps)
__global__ __launch_bounds__(256) void edge_forward(
    const float* __restrict__ cav, const float* __restrict__ C,
    float* __restrict__ temp2, int E)
{
    __shared__ float Cs[Q * Q];
    Cs[threadIdx.x] = C[threadIdx.x];
    __syncthreads();

    int e = blockIdx.x * 256 + threadIdx.x;
    if (e >= E) return;

    const float4* rp = (const float4*)(cav + (size_t)e * Q);
    float4 a0 = rp[0], a1 = rp[1], a2 = rp[2], a3 = rp[3];
    float r[Q] = {a0.x, a0.y, a0.z, a0.w, a1.x, a1.y, a1.z, a1.w,
                  a2.x, a2.y, a2.z, a2.w, a3.x, a3.y, a3.z, a3.w};

    float t[Q];
#pragma unroll
    for (int q = 0; q < Q; ++q) {
        float acc = 0.f;
#pragma unroll
        for (int k = 0; k < Q; ++k) acc += r[k] * Cs[k * Q + q];
        t[q] = __logf(acc + EPS);
    }

    float4* tp = (float4*)(temp2 + (size_t)e * Q);
    tp[0] = make_float4(t[0],  t[1],  t[2],  t[3]);
    tp[1] = make_float4(t[4],  t[5],  t[6],  t[7]);
    tp[2] = make_float4(t[8],  t[9],  t[10], t[11]);
    tp[3] = make_float4(t[12], t[13], t[14], t[15]);
}

// Rounds 2..DEPTH: fused softmax + matmul + log, cav never materialized.
// temp2_new[e] = log(softmax(marg[src[e]] - temp2_old[ind[e]]) @ C + eps)
//             = log(u@C + eps*s) - log(s),  u = exp(x - mx), s = sum(u)
__global__ __launch_bounds__(256) void fused_edge(
    const float* __restrict__ marg, const float* __restrict__ temp2_old,
    const int* __restrict__ a1_src, const int* __restrict__ indice_ij,
    const float* __restrict__ C, float* __restrict__ temp2_new, int E)
{
    __shared__ float Cs[Q * Q];
    Cs[threadIdx.x] = C[threadIdx.x];
    __syncthreads();

    int e = blockIdx.x * 256 + threadIdx.x;
    if (e >= E) return;

    const float4* mp = (const float4*)(marg      + (size_t)a1_src[e]    * Q);
    const float4* tp = (const float4*)(temp2_old + (size_t)indice_ij[e] * Q);
    float4 m0 = mp[0], m1 = mp[1], m2 = mp[2], m3 = mp[3];
    float4 t0 = tp[0], t1 = tp[1], t2 = tp[2], t3 = tp[3];

    float x[Q] = {m0.x - t0.x, m0.y - t0.y, m0.z - t0.z, m0.w - t0.w,
                  m1.x - t1.x, m1.y - t1.y, m1.z - t1.z, m1.w - t1.w,
                  m2.x - t2.x, m2.y - t2.y, m2.z - t2.z, m2.w - t2.w,
                  m3.x - t3.x, m3.y - t3.y, m3.z - t3.z, m3.w - t3.w};

    float mx = x[0];
#pragma unroll
    for (int q = 1; q < Q; ++q) mx = fmaxf(mx, x[q]);
    float u[Q];
    float s = 0.f;
#pragma unroll
    for (int q = 0; q < Q; ++q) { u[q] = __expf(x[q] - mx); s += u[q]; }
    float logs = __logf(s);

    float t[Q];
#pragma unroll
    for (int q = 0; q < Q; ++q) {
        float acc = EPS * s;
#pragma unroll
        for (int k = 0; k < Q; ++k) acc += u[k] * Cs[k * Q + q];
        t[q] = __logf(acc) - logs;
    }

    float4* op = (float4*)(temp2_new + (size_t)e * Q);
    op[0] = make_float4(t[0],  t[1],  t[2],  t[3]);
    op[1] = make_float4(t[4],  t[5],  t[6],  t[7]);
    op[2] = make_float4(t[8],  t[9],  t[10], t[11]);
    op[3] = make_float4(t[12], t[13], t[14], t[15]);
}

// one wave per node: marg[i] = field[i] + sum over its edges of temp2 rows
__global__ __launch_bounds__(256) void node_reduce(
    const float* __restrict__ temp2, const int* __restrict__ perm,
    const int* __restrict__ start, const float* __restrict__ field,
    float* __restrict__ marg, int N)
{
    int wave = threadIdx.x >> 6;
    int node = blockIdx.x * 4 + wave;
    if (node >= N) return;
    int lane = threadIdx.x & 63;
    int sub = lane >> 4;
    int q = lane & 15;

    int lo = start[node], hi = start[node + 1];
    float acc = 0.f;
    for (int j = lo + sub; j < hi; j += 4) {
        int e = perm[j];
        acc += temp2[(size_t)e * Q + q];
    }
    acc += __shfl_xor(acc, 16, 64);
    acc += __shfl_xor(acc, 32, 64);
    if (lane < 16)
        marg[(size_t)node * Q + q] = acc + field[(size_t)node * Q + q];
}

// final: per node log_softmax
__global__ __launch_bounds__(256) void node_out(
    const float* __restrict__ marg, float* __restrict__ out, int N)
{
    int i = blockIdx.x * 256 + threadIdx.x;
    if (i >= N) return;

    const float4* mp = (const float4*)(marg + (size_t)i * Q);
    float4 m0 = mp[0], m1 = mp[1], m2 = mp[2], m3 = mp[3];
    float x[Q] = {m0.x, m0.y, m0.z, m0.w, m1.x, m1.y, m1.z, m1.w,
                  m2.x, m2.y, m2.z, m2.w, m3.x, m3.y, m3.z, m3.w};

    float mx = x[0];
#pragma unroll
    for (int q = 1; q < Q; ++q) mx = fmaxf(mx, x[q]);
    float s = 0.f;
#pragma unroll
    for (int q = 0; q < Q; ++q) s += __expf(x[q] - mx);
    float lse = mx + __logf(s);

    float4* op = (float4*)(out + (size_t)i * Q);
    op[0] = make_float4(x[0]  - lse, x[1]  - lse, x[2]  - lse, x[3]  - lse);
    op[1] = make_float4(x[4]  - lse, x[5]  - lse, x[6]  - lse, x[7]  - lse);
    op[2] = make_float4(x[8]  - lse, x[9]  - lse, x[10] - lse, x[11] - lse);
    op[3] = make_float4(x[12] - lse, x[13] - lse, x[14] - lse, x[15] - lse);
}

extern "C" void kernel_launch(void* const* d_in, const int* in_sizes, int n_in,
                              void* d_out, int out_size, void* d_ws, size_t ws_size,
                              hipStream_t stream) {
    // inputs: 0 marg_i (dead), 1 cav_ij, 2 C, 3 field_i, 4 edge_dst, 5 a1_src, 6 indice_ij
    const float* cav_in   = (const float*)d_in[1];
    const float* C        = (const float*)d_in[2];
    const float* field_i  = (const float*)d_in[3];
    const int*   edge_dst = (const int*)d_in[4];
    const int*   a1_src   = (const int*)d_in[5];
    const int*   indice   = (const int*)d_in[6];
    float* out = (float*)d_out;

    const int E = in_sizes[4];
    const int N = in_sizes[0] / Q;

    char* ws = (char*)d_ws;
    const size_t edge_bytes = (size_t)E * Q * sizeof(float);
    const size_t node_bytes = (size_t)N * Q * sizeof(float);
    float* t2a  = (float*)ws;                                    // [E,Q]
    float* t2b  = (float*)(ws + edge_bytes);                     // [E,Q]
    float* marg = (float*)(ws + 2 * edge_bytes);                 // [N,Q]
    char*  p    = ws + 2 * edge_bytes + node_bytes;
    int* perm   = (int*)p;                 p += (size_t)E * 4;
    int* count  = (int*)p;                 p += (size_t)N * 4;
    int* start  = (int*)p;                 p += (size_t)(N + 1) * 4;
    int* cursor = (int*)p;

    const int eb = 256;
    const int eg = (E + eb - 1) / eb;
    const int ng = (N + eb - 1) / eb;
    const int rg = (N + 3) / 4;

    // ---- one-time CSR build ----
    hipMemsetAsync(count, 0, (size_t)N * 4, stream);
    hist_kernel<<<eg, eb, 0, stream>>>(edge_dst, count, E);
    scan_kernel<<<1, 1024, 0, stream>>>(count, start, N);
    hipMemcpyAsync(cursor, start, (size_t)N * 4, hipMemcpyDeviceToDevice, stream);
    scatter_kernel<<<eg, eb, 0, stream>>>(edge_dst, cursor, perm, E);

    // ---- round 1 ----
    float* t_cur = t2a;
    float* t_nxt = t2b;
    edge_forward<<<eg, eb, 0, stream>>>(cav_in, C, t_cur, E);
    node_reduce<<<rg, eb, 0, stream>>>(t_cur, perm, start, field_i, marg, N);

    // ---- rounds 2..DEPTH (cav fused away) ----
    for (int it = 1; it < DEPTH; ++it) {
        fused_edge<<<eg, eb, 0, stream>>>(marg, t_cur, a1_src, indice, C, t_nxt, E);
        node_reduce<<<rg, eb, 0, stream>>>(t_nxt, perm, start, field_i, marg, N);
        float* tmp = t_cur; t_cur = t_nxt; t_nxt = tmp;
    }

    node_out<<<ng, eb, 0, stream>>>(marg, out, N);
}

// Round 4
// 850.777 us; speedup vs baseline: 8.2624x; 1.1522x over previous
//
#include <hip/hip_runtime.h>

#define Q 16
#define EPS 1e-8f
#define DEPTH 5

// ---------- one-time CSR build (edge_dst constant across rounds) ----------

__global__ __launch_bounds__(256) void hist_kernel(
    const int* __restrict__ dst, int* __restrict__ count, int E)
{
    int e = blockIdx.x * 256 + threadIdx.x;
    if (e < E) atomicAdd(&count[dst[e]], 1);
}

// single-block exclusive scan of count[0..N) -> start[0..N]
__global__ __launch_bounds__(1024) void scan_kernel(
    const int* __restrict__ count, int* __restrict__ start, int N)
{
    __shared__ int part[1024];
    const int t = threadIdx.x;
    const int chunk = (N + 1023) / 1024;
    const int lo = t * chunk;
    const int hi = min(lo + chunk, N);

    int s = 0;
    for (int i = lo; i < hi; ++i) s += count[i];
    part[t] = s;
    __syncthreads();

    for (int off = 1; off < 1024; off <<= 1) {
        int u = (t >= off) ? part[t - off] : 0;
        __syncthreads();
        part[t] += u;
        __syncthreads();
    }

    int base = part[t] - s;
    int run = base;
    for (int i = lo; i < hi; ++i) { start[i] = run; run += count[i]; }
    if (t == 1023) start[N] = part[1023];
}

// pos[e] = slot of edge e in dst-sorted order. Coalesced write (no perm array).
__global__ __launch_bounds__(256) void rank_kernel(
    const int* __restrict__ dst, int* __restrict__ cursor,
    int* __restrict__ pos, int E)
{
    int e = blockIdx.x * 256 + threadIdx.x;
    if (e < E) pos[e] = atomicAdd(&cursor[dst[e]], 1);
}

// ind2[e] = pos[indice_ij[e]]  (remap gather index into sorted temp2 space)
__global__ __launch_bounds__(256) void compose_kernel(
    const int* __restrict__ indice, const int* __restrict__ pos,
    int* __restrict__ ind2, int E)
{
    int e = blockIdx.x * 256 + threadIdx.x;
    if (e < E) ind2[e] = pos[indice[e]];
}

// ---------- per-round kernels ----------

// Round 1: t2s[pos[e]] = log(cav_in[e]@C + eps)  (row = one aligned 64B line)
__global__ __launch_bounds__(256) void edge_forward(
    const float* __restrict__ cav, const float* __restrict__ C,
    const int* __restrict__ pos, float* __restrict__ t2s, int E)
{
    __shared__ float Cs[Q * Q];
    Cs[threadIdx.x] = C[threadIdx.x];
    __syncthreads();

    int e = blockIdx.x * 256 + threadIdx.x;
    if (e >= E) return;

    const float4* rp = (const float4*)(cav + (size_t)e * Q);
    float4 a0 = rp[0], a1 = rp[1], a2 = rp[2], a3 = rp[3];
    float r[Q] = {a0.x, a0.y, a0.z, a0.w, a1.x, a1.y, a1.z, a1.w,
                  a2.x, a2.y, a2.z, a2.w, a3.x, a3.y, a3.z, a3.w};

    float t[Q];
#pragma unroll
    for (int q = 0; q < Q; ++q) {
        float acc = 0.f;
#pragma unroll
        for (int k = 0; k < Q; ++k) acc += r[k] * Cs[k * Q + q];
        t[q] = __logf(acc + EPS);
    }

    float4* op = (float4*)(t2s + (size_t)pos[e] * Q);
    op[0] = make_float4(t[0],  t[1],  t[2],  t[3]);
    op[1] = make_float4(t[4],  t[5],  t[6],  t[7]);
    op[2] = make_float4(t[8],  t[9],  t[10], t[11]);
    op[3] = make_float4(t[12], t[13], t[14], t[15]);
}

// Rounds 2..DEPTH: fused softmax+matmul+log; reads sorted t2_old via ind2,
// writes sorted t2_new via pos. cav never materialized.
__global__ __launch_bounds__(256) void fused_edge(
    const float* __restrict__ marg, const float* __restrict__ t2_old,
    const int* __restrict__ a1_src, const int* __restrict__ ind2,
    const int* __restrict__ pos, const float* __restrict__ C,
    float* __restrict__ t2_new, int E)
{
    __shared__ float Cs[Q * Q];
    Cs[threadIdx.x] = C[threadIdx.x];
    __syncthreads();

    int e = blockIdx.x * 256 + threadIdx.x;
    if (e >= E) return;

    const float4* mp = (const float4*)(marg   + (size_t)a1_src[e] * Q);
    const float4* tp = (const float4*)(t2_old + (size_t)ind2[e]   * Q);
    float4 m0 = mp[0], m1 = mp[1], m2 = mp[2], m3 = mp[3];
    float4 t0 = tp[0], t1 = tp[1], t2 = tp[2], t3 = tp[3];

    float x[Q] = {m0.x - t0.x, m0.y - t0.y, m0.z - t0.z, m0.w - t0.w,
                  m1.x - t1.x, m1.y - t1.y, m1.z - t1.z, m1.w - t1.w,
                  m2.x - t2.x, m2.y - t2.y, m2.z - t2.z, m2.w - t2.w,
                  m3.x - t3.x, m3.y - t3.y, m3.z - t3.z, m3.w - t3.w};

    float mx = x[0];
#pragma unroll
    for (int q = 1; q < Q; ++q) mx = fmaxf(mx, x[q]);
    float u[Q];
    float s = 0.f;
#pragma unroll
    for (int q = 0; q < Q; ++q) { u[q] = __expf(x[q] - mx); s += u[q]; }
    float logs = __logf(s);

    float t[Q];
#pragma unroll
    for (int q = 0; q < Q; ++q) {
        float acc = EPS * s;
#pragma unroll
        for (int k = 0; k < Q; ++k) acc += u[k] * Cs[k * Q + q];
        t[q] = __logf(acc) - logs;
    }

    float4* op = (float4*)(t2_new + (size_t)pos[e] * Q);
    op[0] = make_float4(t[0],  t[1],  t[2],  t[3]);
    op[1] = make_float4(t[4],  t[5],  t[6],  t[7]);
    op[2] = make_float4(t[8],  t[9],  t[10], t[11]);
    op[3] = make_float4(t[12], t[13], t[14], t[15]);
}

// one wave per node; t2s rows for this node are CONTIGUOUS [start,start+1).
// float4 per lane -> wave streams 16 rows (1 KB) per iteration.
__global__ __launch_bounds__(256) void node_reduce(
    const float* __restrict__ t2s, const int* __restrict__ start,
    const float* __restrict__ field, float* __restrict__ marg, int N)
{
    int wave = threadIdx.x >> 6;
    int node = blockIdx.x * 4 + wave;
    if (node >= N) return;
    int lane = threadIdx.x & 63;

    size_t flo = (size_t)start[node] * Q;
    size_t fhi = (size_t)start[node + 1] * Q;

    float4 acc = make_float4(0.f, 0.f, 0.f, 0.f);
    for (size_t f = flo + (size_t)lane * 4; f < fhi; f += 256) {
        const float4 v = *(const float4*)(t2s + f);
        acc.x += v.x; acc.y += v.y; acc.z += v.z; acc.w += v.w;
    }
    // lanes sharing lane&3 hold the same 4 columns; reduce over bits 2..5
#pragma unroll
    for (int m = 4; m <= 32; m <<= 1) {
        acc.x += __shfl_xor(acc.x, m, 64);
        acc.y += __shfl_xor(acc.y, m, 64);
        acc.z += __shfl_xor(acc.z, m, 64);
        acc.w += __shfl_xor(acc.w, m, 64);
    }
    if (lane < 4) {
        const float4 fv = *(const float4*)(field + (size_t)node * Q + lane * 4);
        float4 r = make_float4(acc.x + fv.x, acc.y + fv.y,
                               acc.z + fv.z, acc.w + fv.w);
        *(float4*)(marg + (size_t)node * Q + lane * 4) = r;
    }
}

// final: per node log_softmax
__global__ __launch_bounds__(256) void node_out(
    const float* __restrict__ marg, float* __restrict__ out, int N)
{
    int i = blockIdx.x * 256 + threadIdx.x;
    if (i >= N) return;

    const float4* mp = (const float4*)(marg + (size_t)i * Q);
    float4 m0 = mp[0], m1 = mp[1], m2 = mp[2], m3 = mp[3];
    float x[Q] = {m0.x, m0.y, m0.z, m0.w, m1.x, m1.y, m1.z, m1.w,
                  m2.x, m2.y, m2.z, m2.w, m3.x, m3.y, m3.z, m3.w};

    float mx = x[0];
#pragma unroll
    for (int q = 1; q < Q; ++q) mx = fmaxf(mx, x[q]);
    float s = 0.f;
#pragma unroll
    for (int q = 0; q < Q; ++q) s += __expf(x[q] - mx);
    float lse = mx + __logf(s);

    float4* op = (float4*)(out + (size_t)i * Q);
    op[0] = make_float4(x[0]  - lse, x[1]  - lse, x[2]  - lse, x[3]  - lse);
    op[1] = make_float4(x[4]  - lse, x[5]  - lse, x[6]  - lse, x[7]  - lse);
    op[2] = make_float4(x[8]  - lse, x[9]  - lse, x[10] - lse, x[11] - lse);
    op[3] = make_float4(x[12] - lse, x[13] - lse, x[14] - lse, x[15] - lse);
}

extern "C" void kernel_launch(void* const* d_in, const int* in_sizes, int n_in,
                              void* d_out, int out_size, void* d_ws, size_t ws_size,
                              hipStream_t stream) {
    // inputs: 0 marg_i (dead), 1 cav_ij, 2 C, 3 field_i, 4 edge_dst, 5 a1_src, 6 indice_ij
    const float* cav_in   = (const float*)d_in[1];
    const float* C        = (const float*)d_in[2];
    const float* field_i  = (const float*)d_in[3];
    const int*   edge_dst = (const int*)d_in[4];
    const int*   a1_src   = (const int*)d_in[5];
    const int*   indice   = (const int*)d_in[6];
    float* out = (float*)d_out;

    const int E = in_sizes[4];
    const int N = in_sizes[0] / Q;

    char* ws = (char*)d_ws;
    const size_t edge_bytes = (size_t)E * Q * sizeof(float);
    const size_t node_bytes = (size_t)N * Q * sizeof(float);
    float* t2a  = (float*)ws;                                    // [E,Q] sorted
    float* t2b  = (float*)(ws + edge_bytes);                     // [E,Q] sorted
    float* marg = (float*)(ws + 2 * edge_bytes);                 // [N,Q]
    char*  p    = ws + 2 * edge_bytes + node_bytes;
    int* pos    = (int*)p;                 p += (size_t)E * 4;   // [E]
    int* ind2   = (int*)p;                 p += (size_t)E * 4;   // [E]
    int* count  = (int*)p;                 p += (size_t)N * 4;   // [N]
    int* start  = (int*)p;                 p += (size_t)(N + 1) * 4;
    int* cursor = (int*)p;                                        // [N]

    const int eb = 256;
    const int eg = (E + eb - 1) / eb;
    const int ng = (N + eb - 1) / eb;
    const int rg = (N + 3) / 4;

    // ---- one-time sort-position build ----
    hipMemsetAsync(count, 0, (size_t)N * 4, stream);
    hist_kernel<<<eg, eb, 0, stream>>>(edge_dst, count, E);
    scan_kernel<<<1, 1024, 0, stream>>>(count, start, N);
    hipMemcpyAsync(cursor, start, (size_t)N * 4, hipMemcpyDeviceToDevice, stream);
    rank_kernel<<<eg, eb, 0, stream>>>(edge_dst, cursor, pos, E);
    compose_kernel<<<eg, eb, 0, stream>>>(indice, pos, ind2, E);

    // ---- round 1 ----
    float* t_cur = t2a;
    float* t_nxt = t2b;
    edge_forward<<<eg, eb, 0, stream>>>(cav_in, C, pos, t_cur, E);
    node_reduce<<<rg, eb, 0, stream>>>(t_cur, start, field_i, marg, N);

    // ---- rounds 2..DEPTH ----
    for (int it = 1; it < DEPTH; ++it) {
        fused_edge<<<eg, eb, 0, stream>>>(marg, t_cur, a1_src, ind2, pos, C, t_nxt, E);
        node_reduce<<<rg, eb, 0, stream>>>(t_nxt, start, field_i, marg, N);
        float* tmp = t_cur; t_cur = t_nxt; t_nxt = tmp;
    }

    node_out<<<ng, eb, 0, stream>>>(marg, out, N);
}

// Round 5
// 798.902 us; speedup vs baseline: 8.7989x; 1.0649x over previous
//
#include <hip/hip_runtime.h>
#include <hip/hip_fp16.h>

#define Q 16
#define EPS 1e-8f
#define DEPTH 5

typedef unsigned int u32;

__device__ __forceinline__ u32 pack2(float a, float b) {
    __half2 h = __floats2half2_rn(a, b);
    return *(u32*)&h;
}
__device__ __forceinline__ float2 unpack2(u32 u) {
    __half2 h = *(__half2*)&u;
    return __half22float2(h);
}

// ---------- one-time CSR build (edge_dst constant across rounds) ----------

__global__ __launch_bounds__(256) void hist_kernel(
    const int* __restrict__ dst, int* __restrict__ count, int E)
{
    int e = blockIdx.x * 256 + threadIdx.x;
    if (e < E) atomicAdd(&count[dst[e]], 1);
}

__global__ __launch_bounds__(1024) void scan_kernel(
    const int* __restrict__ count, int* __restrict__ start, int N)
{
    __shared__ int part[1024];
    const int t = threadIdx.x;
    const int chunk = (N + 1023) / 1024;
    const int lo = t * chunk;
    const int hi = min(lo + chunk, N);

    int s = 0;
    for (int i = lo; i < hi; ++i) s += count[i];
    part[t] = s;
    __syncthreads();

    for (int off = 1; off < 1024; off <<= 1) {
        int u = (t >= off) ? part[t - off] : 0;
        __syncthreads();
        part[t] += u;
        __syncthreads();
    }

    int base = part[t] - s;
    int run = base;
    for (int i = lo; i < hi; ++i) { start[i] = run; run += count[i]; }
    if (t == 1023) start[N] = part[1023];
}

// pos[e] = slot of edge e in dst-sorted order (coalesced write)
__global__ __launch_bounds__(256) void rank_kernel(
    const int* __restrict__ dst, int* __restrict__ cursor,
    int* __restrict__ pos, int E)
{
    int e = blockIdx.x * 256 + threadIdx.x;
    if (e < E) pos[e] = atomicAdd(&cursor[dst[e]], 1);
}

// ind2[e] = pos[indice_ij[e]]
__global__ __launch_bounds__(256) void compose_kernel(
    const int* __restrict__ indice, const int* __restrict__ pos,
    int* __restrict__ ind2, int E)
{
    int e = blockIdx.x * 256 + threadIdx.x;
    if (e < E) ind2[e] = pos[indice[e]];
}

// ---------- per-round kernels ----------
// temp2 stored as fp16, row = 16 halfs = 8 u32 = 32B, in dst-sorted order.

// Round 1: t2s[pos[e]] = log(cav_in[e]@C + eps)
__global__ __launch_bounds__(256) void edge_forward(
    const float* __restrict__ cav, const float* __restrict__ C,
    const int* __restrict__ pos, u32* __restrict__ t2s, int E)
{
    __shared__ float Cs[Q * Q];
    Cs[threadIdx.x] = C[threadIdx.x];
    __syncthreads();

    int e = blockIdx.x * 256 + threadIdx.x;
    if (e >= E) return;

    const float4* rp = (const float4*)(cav + (size_t)e * Q);
    float4 a0 = rp[0], a1 = rp[1], a2 = rp[2], a3 = rp[3];
    float r[Q] = {a0.x, a0.y, a0.z, a0.w, a1.x, a1.y, a1.z, a1.w,
                  a2.x, a2.y, a2.z, a2.w, a3.x, a3.y, a3.z, a3.w};

    float t[Q];
#pragma unroll
    for (int q = 0; q < Q; ++q) {
        float acc = 0.f;
#pragma unroll
        for (int k = 0; k < Q; ++k) acc += r[k] * Cs[k * Q + q];
        t[q] = __logf(acc + EPS);
    }

    uint4 w0, w1;
    w0.x = pack2(t[0],  t[1]);  w0.y = pack2(t[2],  t[3]);
    w0.z = pack2(t[4],  t[5]);  w0.w = pack2(t[6],  t[7]);
    w1.x = pack2(t[8],  t[9]);  w1.y = pack2(t[10], t[11]);
    w1.z = pack2(t[12], t[13]); w1.w = pack2(t[14], t[15]);
    uint4* op = (uint4*)(t2s + (size_t)pos[e] * 8);
    op[0] = w0; op[1] = w1;
}

// Rounds 2..DEPTH: t2_new[pos[e]] = log(softmax(marg[src]-t2_old[ind2]) @ C + eps)
__global__ __launch_bounds__(256) void fused_edge(
    const float* __restrict__ marg, const u32* __restrict__ t2_old,
    const int* __restrict__ a1_src, const int* __restrict__ ind2,
    const int* __restrict__ pos, const float* __restrict__ C,
    u32* __restrict__ t2_new, int E)
{
    __shared__ float Cs[Q * Q];
    Cs[threadIdx.x] = C[threadIdx.x];
    __syncthreads();

    int e = blockIdx.x * 256 + threadIdx.x;
    if (e >= E) return;

    const float4* mp = (const float4*)(marg + (size_t)a1_src[e] * Q);
    const uint4*  tp = (const uint4*)(t2_old + (size_t)ind2[e] * 8);
    float4 m0 = mp[0], m1 = mp[1], m2 = mp[2], m3 = mp[3];
    uint4 r0 = tp[0], r1 = tp[1];
    float2 p0 = unpack2(r0.x), p1 = unpack2(r0.y), p2 = unpack2(r0.z), p3 = unpack2(r0.w);
    float2 p4 = unpack2(r1.x), p5 = unpack2(r1.y), p6 = unpack2(r1.z), p7 = unpack2(r1.w);

    float x[Q] = {m0.x - p0.x, m0.y - p0.y, m0.z - p1.x, m0.w - p1.y,
                  m1.x - p2.x, m1.y - p2.y, m1.z - p3.x, m1.w - p3.y,
                  m2.x - p4.x, m2.y - p4.y, m2.z - p5.x, m2.w - p5.y,
                  m3.x - p6.x, m3.y - p6.y, m3.z - p7.x, m3.w - p7.y};

    float mx = x[0];
#pragma unroll
    for (int q = 1; q < Q; ++q) mx = fmaxf(mx, x[q]);
    float u[Q];
    float s = 0.f;
#pragma unroll
    for (int q = 0; q < Q; ++q) { u[q] = __expf(x[q] - mx); s += u[q]; }
    float logs = __logf(s);

    float t[Q];
#pragma unroll
    for (int q = 0; q < Q; ++q) {
        float acc = EPS * s;
#pragma unroll
        for (int k = 0; k < Q; ++k) acc += u[k] * Cs[k * Q + q];
        t[q] = __logf(acc) - logs;
    }

    uint4 w0, w1;
    w0.x = pack2(t[0],  t[1]);  w0.y = pack2(t[2],  t[3]);
    w0.z = pack2(t[4],  t[5]);  w0.w = pack2(t[6],  t[7]);
    w1.x = pack2(t[8],  t[9]);  w1.y = pack2(t[10], t[11]);
    w1.z = pack2(t[12], t[13]); w1.w = pack2(t[14], t[15]);
    uint4* op = (uint4*)(t2_new + (size_t)pos[e] * 8);
    op[0] = w0; op[1] = w1;
}

// one wave per node; rows contiguous. Lane reads uint2 (4 halfs = 8B);
// wave streams 16 rows (512B) per iteration. Lane covers columns (lane&3)*4..+3.
__global__ __launch_bounds__(256) void node_reduce(
    const u32* __restrict__ t2s, const int* __restrict__ start,
    const float* __restrict__ field, float* __restrict__ marg, int N)
{
    int wave = threadIdx.x >> 6;
    int node = blockIdx.x * 4 + wave;
    if (node >= N) return;
    int lane = threadIdx.x & 63;

    size_t flo = (size_t)start[node] * 8;
    size_t fhi = (size_t)start[node + 1] * 8;

    float4 acc = make_float4(0.f, 0.f, 0.f, 0.f);
    for (size_t f = flo + (size_t)lane * 2; f < fhi; f += 128) {
        uint2 v = *(const uint2*)(t2s + f);
        float2 a = unpack2(v.x), b = unpack2(v.y);
        acc.x += a.x; acc.y += a.y; acc.z += b.x; acc.w += b.y;
    }
#pragma unroll
    for (int m = 4; m <= 32; m <<= 1) {
        acc.x += __shfl_xor(acc.x, m, 64);
        acc.y += __shfl_xor(acc.y, m, 64);
        acc.z += __shfl_xor(acc.z, m, 64);
        acc.w += __shfl_xor(acc.w, m, 64);
    }
    if (lane < 4) {
        const float4 fv = *(const float4*)(field + (size_t)node * Q + lane * 4);
        float4 r = make_float4(acc.x + fv.x, acc.y + fv.y,
                               acc.z + fv.z, acc.w + fv.w);
        *(float4*)(marg + (size_t)node * Q + lane * 4) = r;
    }
}

// Final round: node_reduce fused with log_softmax, writes out directly.
__global__ __launch_bounds__(256) void node_reduce_out(
    const u32* __restrict__ t2s, const int* __restrict__ start,
    const float* __restrict__ field, float* __restrict__ out, int N)
{
    int wave = threadIdx.x >> 6;
    int node = blockIdx.x * 4 + wave;
    if (node >= N) return;
    int lane = threadIdx.x & 63;

    size_t flo = (size_t)start[node] * 8;
    size_t fhi = (size_t)start[node + 1] * 8;

    float4 acc = make_float4(0.f, 0.f, 0.f, 0.f);
    for (size_t f = flo + (size_t)lane * 2; f < fhi; f += 128) {
        uint2 v = *(const uint2*)(t2s + f);
        float2 a = unpack2(v.x), b = unpack2(v.y);
        acc.x += a.x; acc.y += a.y; acc.z += b.x; acc.w += b.y;
    }
#pragma unroll
    for (int m = 4; m <= 32; m <<= 1) {
        acc.x += __shfl_xor(acc.x, m, 64);
        acc.y += __shfl_xor(acc.y, m, 64);
        acc.z += __shfl_xor(acc.z, m, 64);
        acc.w += __shfl_xor(acc.w, m, 64);
    }
    // lane l holds columns (l&3)*4..+3 (duplicated across l>>2)
    const float4 fv = *(const float4*)(field + (size_t)node * Q + (lane & 3) * 4);
    float4 r = make_float4(acc.x + fv.x, acc.y + fv.y, acc.z + fv.z, acc.w + fv.w);

    float mx = fmaxf(fmaxf(r.x, r.y), fmaxf(r.z, r.w));
    mx = fmaxf(mx, __shfl_xor(mx, 1, 64));
    mx = fmaxf(mx, __shfl_xor(mx, 2, 64));
    float s = __expf(r.x - mx) + __expf(r.y - mx) + __expf(r.z - mx) + __expf(r.w - mx);
    s += __shfl_xor(s, 1, 64);
    s += __shfl_xor(s, 2, 64);
    float lse = mx + __logf(s);

    if (lane < 4) {
        float4 o = make_float4(r.x - lse, r.y - lse, r.z - lse, r.w - lse);
        *(float4*)(out + (size_t)node * Q + lane * 4) = o;
    }
}

extern "C" void kernel_launch(void* const* d_in, const int* in_sizes, int n_in,
                              void* d_out, int out_size, void* d_ws, size_t ws_size,
                              hipStream_t stream) {
    // inputs: 0 marg_i (dead), 1 cav_ij, 2 C, 3 field_i, 4 edge_dst, 5 a1_src, 6 indice_ij
    const float* cav_in   = (const float*)d_in[1];
    const float* C        = (const float*)d_in[2];
    const float* field_i  = (const float*)d_in[3];
    const int*   edge_dst = (const int*)d_in[4];
    const int*   a1_src   = (const int*)d_in[5];
    const int*   indice   = (const int*)d_in[6];
    float* out = (float*)d_out;

    const int E = in_sizes[4];
    const int N = in_sizes[0] / Q;

    char* ws = (char*)d_ws;
    const size_t t2_bytes   = (size_t)E * 32;            // fp16 rows
    const size_t node_bytes = (size_t)N * Q * sizeof(float);
    u32*   t2a  = (u32*)ws;                              // [E,16] fp16, sorted
    u32*   t2b  = (u32*)(ws + t2_bytes);                 // [E,16] fp16, sorted
    float* marg = (float*)(ws + 2 * t2_bytes);           // [N,Q]
    char*  p    = ws + 2 * t2_bytes + node_bytes;
    int* pos    = (int*)p;                 p += (size_t)E * 4;
    int* ind2   = (int*)p;                 p += (size_t)E * 4;
    int* count  = (int*)p;                 p += (size_t)N * 4;
    int* start  = (int*)p;                 p += (size_t)(N + 1) * 4;
    int* cursor = (int*)p;

    const int eb = 256;
    const int eg = (E + eb - 1) / eb;
    const int rg = (N + 3) / 4;

    // ---- one-time sort-position build ----
    hipMemsetAsync(count, 0, (size_t)N * 4, stream);
    hist_kernel<<<eg, eb, 0, stream>>>(edge_dst, count, E);
    scan_kernel<<<1, 1024, 0, stream>>>(count, start, N);
    hipMemcpyAsync(cursor, start, (size_t)N * 4, hipMemcpyDeviceToDevice, stream);
    rank_kernel<<<eg, eb, 0, stream>>>(edge_dst, cursor, pos, E);
    compose_kernel<<<eg, eb, 0, stream>>>(indice, pos, ind2, E);

    // ---- round 1 ----
    u32* t_cur = t2a;
    u32* t_nxt = t2b;
    edge_forward<<<eg, eb, 0, stream>>>(cav_in, C, pos, t_cur, E);
    node_reduce<<<rg, eb, 0, stream>>>(t_cur, start, field_i, marg, N);

    // ---- rounds 2..DEPTH ----
    for (int it = 1; it < DEPTH; ++it) {
        fused_edge<<<eg, eb, 0, stream>>>(marg, t_cur, a1_src, ind2, pos, C, t_nxt, E);
        if (it != DEPTH - 1)
            node_reduce<<<rg, eb, 0, stream>>>(t_nxt, start, field_i, marg, N);
        else
            node_reduce_out<<<rg, eb, 0, stream>>>(t_nxt, start, field_i, out, N);
        u32* tmp = t_cur; t_cur = t_nxt; t_nxt = tmp;
    }
}

// Round 6
// 782.543 us; speedup vs baseline: 8.9828x; 1.0209x over previous
//
#include <hip/hip_runtime.h>
#include <hip/hip_fp16.h>

#define Q 16
#define EPS 1e-8f
#define DEPTH 5

typedef unsigned int u32;

__device__ __forceinline__ u32 pack2(float a, float b) {
    __half2 h = __floats2half2_rn(a, b);
    return *(u32*)&h;
}
__device__ __forceinline__ float2 unpack2(u32 u) {
    __half2 h = *(__half2*)&u;
    return __half22float2(h);
}

// ---------- one-time build: dst-sorted slot metadata ----------

__global__ __launch_bounds__(256) void hist_kernel(
    const int* __restrict__ dst, int* __restrict__ count, int E)
{
    int e = blockIdx.x * 256 + threadIdx.x;
    if (e < E) atomicAdd(&count[dst[e]], 1);
}

__global__ __launch_bounds__(1024) void scan_kernel(
    const int* __restrict__ count, int* __restrict__ start, int N)
{
    __shared__ int part[1024];
    const int t = threadIdx.x;
    const int chunk = (N + 1023) / 1024;
    const int lo = t * chunk;
    const int hi = min(lo + chunk, N);

    int s = 0;
    for (int i = lo; i < hi; ++i) s += count[i];
    part[t] = s;
    __syncthreads();

    for (int off = 1; off < 1024; off <<= 1) {
        int u = (t >= off) ? part[t - off] : 0;
        __syncthreads();
        part[t] += u;
        __syncthreads();
    }

    int base = part[t] - s;
    int run = base;
    for (int i = lo; i < hi; ++i) { start[i] = run; run += count[i]; }
    if (t == 1023) start[N] = part[1023];
}

// pos[e] = slot of edge e in dst-sorted order (coalesced write)
__global__ __launch_bounds__(256) void rank_kernel(
    const int* __restrict__ dst, int* __restrict__ cursor,
    int* __restrict__ pos, int E)
{
    int e = blockIdx.x * 256 + threadIdx.x;
    if (e < E) pos[e] = atomicAdd(&cursor[dst[e]], 1);
}

// zip[e] = (a1_src[e], pos[indice[e]], dst[e], e)
__global__ __launch_bounds__(256) void compose_zip(
    const int* __restrict__ a1_src, const int* __restrict__ indice,
    const int* __restrict__ dst, const int* __restrict__ pos,
    int4* __restrict__ zip, int E)
{
    int e = blockIdx.x * 256 + threadIdx.x;
    if (e < E) zip[e] = make_int4(a1_src[e], pos[indice[e]], dst[e], e);
}

// sorted[pos[e]] = zip[e]   (single 16B scatter)
__global__ __launch_bounds__(256) void scatter4(
    const int4* __restrict__ zip, const int* __restrict__ pos,
    int4* __restrict__ sorted, int E)
{
    int e = blockIdx.x * 256 + threadIdx.x;
    if (e < E) sorted[pos[e]] = zip[e];
}

// ---------- fused per-round kernel ----------
// MODE 0: round 1 (reads cav via sorted.w), writes t2
// MODE 1: mid rounds (reads marg_in/t2_old via sorted.x/.y), writes t2
// MODE 2: last round (same as 1, but skips the dead t2 write)
// All modes: segment-reduce t rows into marg_out (pre-initialized to field).
template<int MODE>
__global__ __launch_bounds__(256) void fused_round(
    const int4* __restrict__ sorted, const float* __restrict__ C,
    const float* __restrict__ cav,
    const float* __restrict__ marg_in, const u32* __restrict__ t2_old,
    const int* __restrict__ start, const float* __restrict__ field,
    u32* __restrict__ t2_new, float* __restrict__ marg_out, int E)
{
    __shared__ float Cs[Q * Q];
    __shared__ float stage[256 * 17];   // +1 pad breaks bank conflicts
    __shared__ int s_nfirst, s_nlast;

    const int tid = threadIdx.x;
    const int blo = blockIdx.x * 256;
    const int bhi = min(blo + 256, E);
    Cs[tid] = C[tid];
    if (tid == 0) {
        s_nfirst = sorted[blo].z;
        s_nlast  = sorted[bhi - 1].z;
    }
    __syncthreads();

    const int j = blo + tid;
    float t[Q];
    if (j < E) {
        const int4 meta = sorted[j];
        if (MODE == 0) {
            const float4* rp = (const float4*)(cav + (size_t)meta.w * Q);
            float4 a0 = rp[0], a1 = rp[1], a2 = rp[2], a3 = rp[3];
            float r[Q] = {a0.x, a0.y, a0.z, a0.w, a1.x, a1.y, a1.z, a1.w,
                          a2.x, a2.y, a2.z, a2.w, a3.x, a3.y, a3.z, a3.w};
#pragma unroll
            for (int q = 0; q < Q; ++q) {
                float acc = EPS;
#pragma unroll
                for (int k = 0; k < Q; ++k) acc += r[k] * Cs[k * Q + q];
                t[q] = __logf(acc);
            }
        } else {
            const float4* mp = (const float4*)(marg_in + (size_t)meta.x * Q);
            const uint4*  tp = (const uint4*)(t2_old + (size_t)meta.y * 8);
            float4 m0 = mp[0], m1 = mp[1], m2 = mp[2], m3 = mp[3];
            uint4 r0 = tp[0], r1 = tp[1];
            float2 p0 = unpack2(r0.x), p1 = unpack2(r0.y),
                   p2 = unpack2(r0.z), p3 = unpack2(r0.w);
            float2 p4 = unpack2(r1.x), p5 = unpack2(r1.y),
                   p6 = unpack2(r1.z), p7 = unpack2(r1.w);

            float x[Q] = {m0.x - p0.x, m0.y - p0.y, m0.z - p1.x, m0.w - p1.y,
                          m1.x - p2.x, m1.y - p2.y, m1.z - p3.x, m1.w - p3.y,
                          m2.x - p4.x, m2.y - p4.y, m2.z - p5.x, m2.w - p5.y,
                          m3.x - p6.x, m3.y - p6.y, m3.z - p7.x, m3.w - p7.y};

            float mx = x[0];
#pragma unroll
            for (int q = 1; q < Q; ++q) mx = fmaxf(mx, x[q]);
            float u[Q];
            float s = 0.f;
#pragma unroll
            for (int q = 0; q < Q; ++q) { u[q] = __expf(x[q] - mx); s += u[q]; }
            float logs = __logf(s);
#pragma unroll
            for (int q = 0; q < Q; ++q) {
                float acc = EPS * s;
#pragma unroll
                for (int k = 0; k < Q; ++k) acc += u[k] * Cs[k * Q + q];
                t[q] = __logf(acc) - logs;
            }
        }
        if (MODE != 2) {
            uint4 w0, w1;
            w0.x = pack2(t[0],  t[1]);  w0.y = pack2(t[2],  t[3]);
            w0.z = pack2(t[4],  t[5]);  w0.w = pack2(t[6],  t[7]);
            w1.x = pack2(t[8],  t[9]);  w1.y = pack2(t[10], t[11]);
            w1.z = pack2(t[12], t[13]); w1.w = pack2(t[14], t[15]);
            uint4* op = (uint4*)(t2_new + (size_t)j * 8);   // coalesced stream
            op[0] = w0; op[1] = w1;
        }
    } else {
#pragma unroll
        for (int q = 0; q < Q; ++q) t[q] = 0.f;
    }

    // stage rows for the in-block segmented reduction
#pragma unroll
    for (int q = 0; q < Q; ++q) stage[tid * 17 + q] = t[q];
    __syncthreads();

    const int nfirst = s_nfirst;
    const int ncnt = s_nlast - nfirst + 1;
    for (int k = tid; k < ncnt * Q; k += 256) {
        int ln = k >> 4, q = k & 15;
        int n = nfirst + ln;
        int slo = start[n], shi = start[n + 1];
        int lo = max(slo, blo), hi = min(shi, bhi);
        float s = 0.f;
        for (int sl = lo; sl < hi; ++sl) s += stage[(sl - blo) * 17 + q];
        if (slo >= blo && shi <= bhi)   // node fully inside this block
            marg_out[(size_t)n * Q + q] = s + field[(size_t)n * Q + q];
        else                             // spans blocks: marg pre-init = field
            atomicAdd(marg_out + (size_t)n * Q + q, s);
    }
}

// final: per node log_softmax
__global__ __launch_bounds__(256) void node_out(
    const float* __restrict__ marg, float* __restrict__ out, int N)
{
    int i = blockIdx.x * 256 + threadIdx.x;
    if (i >= N) return;

    const float4* mp = (const float4*)(marg + (size_t)i * Q);
    float4 m0 = mp[0], m1 = mp[1], m2 = mp[2], m3 = mp[3];
    float x[Q] = {m0.x, m0.y, m0.z, m0.w, m1.x, m1.y, m1.z, m1.w,
                  m2.x, m2.y, m2.z, m2.w, m3.x, m3.y, m3.z, m3.w};

    float mx = x[0];
#pragma unroll
    for (int q = 1; q < Q; ++q) mx = fmaxf(mx, x[q]);
    float s = 0.f;
#pragma unroll
    for (int q = 0; q < Q; ++q) s += __expf(x[q] - mx);
    float lse = mx + __logf(s);

    float4* op = (float4*)(out + (size_t)i * Q);
    op[0] = make_float4(x[0]  - lse, x[1]  - lse, x[2]  - lse, x[3]  - lse);
    op[1] = make_float4(x[4]  - lse, x[5]  - lse, x[6]  - lse, x[7]  - lse);
    op[2] = make_float4(x[8]  - lse, x[9]  - lse, x[10] - lse, x[11] - lse);
    op[3] = make_float4(x[12] - lse, x[13] - lse, x[14] - lse, x[15] - lse);
}

extern "C" void kernel_launch(void* const* d_in, const int* in_sizes, int n_in,
                              void* d_out, int out_size, void* d_ws, size_t ws_size,
                              hipStream_t stream) {
    // inputs: 0 marg_i (dead), 1 cav_ij, 2 C, 3 field_i, 4 edge_dst, 5 a1_src, 6 indice_ij
    const float* cav_in   = (const float*)d_in[1];
    const float* C        = (const float*)d_in[2];
    const float* field_i  = (const float*)d_in[3];
    const int*   edge_dst = (const int*)d_in[4];
    const int*   a1_src   = (const int*)d_in[5];
    const int*   indice   = (const int*)d_in[6];
    float* out = (float*)d_out;

    const int E = in_sizes[4];
    const int N = in_sizes[0] / Q;

    char* ws = (char*)d_ws;
    const size_t t2_bytes   = (size_t)E * 32;            // fp16 rows, 32B each
    const size_t i4_bytes   = (size_t)E * 16;
    const size_t node_bytes = (size_t)N * Q * sizeof(float);
    u32*   t2a    = (u32*)ws;                     ws += t2_bytes;
    u32*   t2b    = (u32*)ws;                     ws += t2_bytes;
    int4*  zip    = (int4*)ws;                    ws += i4_bytes;
    int4*  sorted = (int4*)ws;                    ws += i4_bytes;
    float* marg_a = (float*)ws;                   ws += node_bytes;
    float* marg_b = (float*)ws;                   ws += node_bytes;
    int*   pos    = (int*)ws;                     ws += (size_t)E * 4;
    int*   count  = (int*)ws;                     ws += (size_t)N * 4;
    int*   start  = (int*)ws;                     ws += (size_t)(N + 1) * 4;
    int*   cursor = (int*)ws;

    const int eb = 256;
    const int eg = (E + eb - 1) / eb;
    const int ng = (N + eb - 1) / eb;

    // ---- one-time dst-sorted metadata build ----
    hipMemsetAsync(count, 0, (size_t)N * 4, stream);
    hist_kernel<<<eg, eb, 0, stream>>>(edge_dst, count, E);
    scan_kernel<<<1, 1024, 0, stream>>>(count, start, N);
    hipMemcpyAsync(cursor, start, (size_t)N * 4, hipMemcpyDeviceToDevice, stream);
    rank_kernel<<<eg, eb, 0, stream>>>(edge_dst, cursor, pos, E);
    compose_zip<<<eg, eb, 0, stream>>>(a1_src, indice, edge_dst, pos, zip, E);
    scatter4<<<eg, eb, 0, stream>>>(zip, pos, sorted, E);

    // ---- DEPTH rounds, marg double-buffered (read r-1 while writing r) ----
    u32* t_cur = t2a;
    u32* t_nxt = t2b;
    float* m_in = marg_b;   // unused in round 1
    float* m_out = marg_a;

    for (int it = 0; it < DEPTH; ++it) {
        hipMemcpyAsync(m_out, field_i, node_bytes, hipMemcpyDeviceToDevice, stream);
        if (it == 0)
            fused_round<0><<<eg, eb, 0, stream>>>(sorted, C, cav_in, nullptr,
                                                  nullptr, start, field_i,
                                                  t_cur, m_out, E);
        else if (it != DEPTH - 1)
            fused_round<1><<<eg, eb, 0, stream>>>(sorted, C, nullptr, m_in,
                                                  t_cur, start, field_i,
                                                  t_nxt, m_out, E);
        else
            fused_round<2><<<eg, eb, 0, stream>>>(sorted, C, nullptr, m_in,
                                                  t_cur, start, field_i,
                                                  nullptr, m_out, E);
        if (it != 0) { u32* tt = t_cur; t_cur = t_nxt; t_nxt = tt; }
        float* tm = m_in; m_in = m_out; m_out = tm;
    }

    node_out<<<ng, eb, 0, stream>>>(m_in, out, N);
}

// Round 7
// 731.975 us; speedup vs baseline: 9.6034x; 1.0691x over previous
//
#include <hip/hip_runtime.h>
#include <hip/hip_fp16.h>

#define Q 16
#define EPS 1e-8f
#define DEPTH 5

typedef unsigned int u32;
typedef _Float16 h2 __attribute__((ext_vector_type(2)));

__device__ __forceinline__ u32 pack2(float a, float b) {
    __half2 h = __floats2half2_rn(a, b);
    return *(u32*)&h;
}
__device__ __forceinline__ float2 unpack2(u32 u) {
    __half2 h = *(__half2*)&u;
    return __half22float2(h);
}
__device__ __forceinline__ h2 mkh2(float a, float b) {
    h2 v; v[0] = (_Float16)a; v[1] = (_Float16)b; return v;
}

// ---------- one-time build: dst-sorted slot metadata ----------

__global__ __launch_bounds__(256) void hist_kernel(
    const int* __restrict__ dst, int* __restrict__ count, int E)
{
    int e = blockIdx.x * 256 + threadIdx.x;
    if (e < E) atomicAdd(&count[dst[e]], 1);
}

__global__ __launch_bounds__(1024) void scan_kernel(
    const int* __restrict__ count, int* __restrict__ start, int N)
{
    __shared__ int part[1024];
    const int t = threadIdx.x;
    const int chunk = (N + 1023) / 1024;
    const int lo = t * chunk;
    const int hi = min(lo + chunk, N);

    int s = 0;
    for (int i = lo; i < hi; ++i) s += count[i];
    part[t] = s;
    __syncthreads();

    for (int off = 1; off < 1024; off <<= 1) {
        int u = (t >= off) ? part[t - off] : 0;
        __syncthreads();
        part[t] += u;
        __syncthreads();
    }

    int base = part[t] - s;
    int run = base;
    for (int i = lo; i < hi; ++i) { start[i] = run; run += count[i]; }
    if (t == 1023) start[N] = part[1023];
}

__global__ __launch_bounds__(256) void rank_kernel(
    const int* __restrict__ dst, int* __restrict__ cursor,
    int* __restrict__ pos, int E)
{
    int e = blockIdx.x * 256 + threadIdx.x;
    if (e < E) pos[e] = atomicAdd(&cursor[dst[e]], 1);
}

// zip[e] = (a1_src[e], pos[indice[e]], dst[e], e)
__global__ __launch_bounds__(256) void compose_zip(
    const int* __restrict__ a1_src, const int* __restrict__ indice,
    const int* __restrict__ dst, const int* __restrict__ pos,
    int4* __restrict__ zip, int E)
{
    int e = blockIdx.x * 256 + threadIdx.x;
    if (e < E) zip[e] = make_int4(a1_src[e], pos[indice[e]], dst[e], e);
}

// sorted[pos[e]] = zip[e]   (single 16B scatter)
__global__ __launch_bounds__(256) void scatter4(
    const int4* __restrict__ zip, const int* __restrict__ pos,
    int4* __restrict__ sorted, int E)
{
    int e = blockIdx.x * 256 + threadIdx.x;
    if (e < E) sorted[pos[e]] = zip[e];
}

// meta2[j] = (ind2, dst<<16 | src)   — 8B/slot for rounds 2..DEPTH
__global__ __launch_bounds__(256) void meta_pack(
    const int4* __restrict__ sorted, int2* __restrict__ meta2, int E)
{
    int j = blockIdx.x * 256 + threadIdx.x;
    if (j < E) {
        int4 m = sorted[j];
        meta2[j] = make_int2(m.y, (m.z << 16) | m.x);
    }
}

// ---------- fused per-round kernel ----------
// MODE 0: round 1 (reads cav via sorted.w), writes t2
// MODE 1: mid rounds (reads marg_in/t2_old via meta2), writes t2
// MODE 2: last round (as 1, skips dead t2 write)
// All: segment-reduce t rows into marg_out (pre-initialized to field).
template<int MODE>
__global__ __launch_bounds__(256) void fused_round(
    const int4* __restrict__ sorted, const int2* __restrict__ meta2,
    const float* __restrict__ C,
    const float* __restrict__ cav,
    const float* __restrict__ marg_in, const u32* __restrict__ t2_old,
    const int* __restrict__ start, const float* __restrict__ field,
    u32* __restrict__ t2_new, float* __restrict__ marg_out, int E)
{
    __shared__ __align__(16) h2 Csh[Q * 8];   // column-major fp16: col q = Csh[q*8..q*8+7]
    __shared__ float stage[256 * 17];
    __shared__ int s_nfirst, s_nlast;

    const int tid = threadIdx.x;
    const int blo = blockIdx.x * 256;
    const int bhi = min(blo + 256, E);
    if (tid < 128) {
        int q = tid >> 3, kk = tid & 7;
        Csh[q * 8 + kk] = mkh2(C[(2 * kk) * Q + q], C[(2 * kk + 1) * Q + q]);
    }
    if (tid == 0) {
        if (MODE == 0) {
            s_nfirst = sorted[blo].z;
            s_nlast  = sorted[bhi - 1].z;
        } else {
            s_nfirst = ((u32)meta2[blo].y) >> 16;
            s_nlast  = ((u32)meta2[bhi - 1].y) >> 16;
        }
    }
    __syncthreads();

    const int j = blo + tid;
    float t[Q];
    if (j < E) {
        h2 uh[8];
        float s, logs;
        if (MODE == 0) {
            const int e = sorted[j].w;
            const float4* rp = (const float4*)(cav + (size_t)e * Q);
            float4 a0 = rp[0], a1 = rp[1], a2 = rp[2], a3 = rp[3];
            uh[0] = mkh2(a0.x, a0.y); uh[1] = mkh2(a0.z, a0.w);
            uh[2] = mkh2(a1.x, a1.y); uh[3] = mkh2(a1.z, a1.w);
            uh[4] = mkh2(a2.x, a2.y); uh[5] = mkh2(a2.z, a2.w);
            uh[6] = mkh2(a3.x, a3.y); uh[7] = mkh2(a3.z, a3.w);
            s = 1.f; logs = 0.f;
        } else {
            const int2 meta = meta2[j];
            const int src = meta.y & 0xffff;
            const float4* mp = (const float4*)(marg_in + (size_t)src * Q);
            const uint4*  tp = (const uint4*)(t2_old + (size_t)meta.x * 8);
            float4 m0 = mp[0], m1 = mp[1], m2 = mp[2], m3 = mp[3];
            uint4 r0 = tp[0], r1 = tp[1];
            float2 p0 = unpack2(r0.x), p1 = unpack2(r0.y),
                   p2 = unpack2(r0.z), p3 = unpack2(r0.w);
            float2 p4 = unpack2(r1.x), p5 = unpack2(r1.y),
                   p6 = unpack2(r1.z), p7 = unpack2(r1.w);

            float x[Q] = {m0.x - p0.x, m0.y - p0.y, m0.z - p1.x, m0.w - p1.y,
                          m1.x - p2.x, m1.y - p2.y, m1.z - p3.x, m1.w - p3.y,
                          m2.x - p4.x, m2.y - p4.y, m2.z - p5.x, m2.w - p5.y,
                          m3.x - p6.x, m3.y - p6.y, m3.z - p7.x, m3.w - p7.y};

            float mx = x[0];
#pragma unroll
            for (int q = 1; q < Q; ++q) mx = fmaxf(mx, x[q]);
            float u[Q];
            s = 0.f;
#pragma unroll
            for (int q = 0; q < Q; ++q) { u[q] = __expf(x[q] - mx); s += u[q]; }
            logs = __logf(s);
#pragma unroll
            for (int k = 0; k < 8; ++k) uh[k] = mkh2(u[2 * k], u[2 * k + 1]);
        }

        const float base = EPS * s;
#pragma unroll
        for (int q = 0; q < Q; ++q) {
            const uint4* cp = (const uint4*)&Csh[q * 8];
            h2 col[8];
            ((uint4*)col)[0] = cp[0];
            ((uint4*)col)[1] = cp[1];
            float acc = base;
#pragma unroll
            for (int kk = 0; kk < 8; ++kk)
                acc = __builtin_amdgcn_fdot2(uh[kk], col[kk], acc, false);
            t[q] = __logf(acc) - logs;
        }

        if (MODE != 2) {
            uint4 w0, w1;
            w0.x = pack2(t[0],  t[1]);  w0.y = pack2(t[2],  t[3]);
            w0.z = pack2(t[4],  t[5]);  w0.w = pack2(t[6],  t[7]);
            w1.x = pack2(t[8],  t[9]);  w1.y = pack2(t[10], t[11]);
            w1.z = pack2(t[12], t[13]); w1.w = pack2(t[14], t[15]);
            uint4* op = (uint4*)(t2_new + (size_t)j * 8);   // coalesced stream
            op[0] = w0; op[1] = w1;
        }
    } else {
#pragma unroll
        for (int q = 0; q < Q; ++q) t[q] = 0.f;
    }

#pragma unroll
    for (int q = 0; q < Q; ++q) stage[tid * 17 + q] = t[q];
    __syncthreads();

    const int nfirst = s_nfirst;
    const int ncnt = s_nlast - nfirst + 1;
    for (int k = tid; k < ncnt * Q; k += 256) {
        int ln = k >> 4, q = k & 15;
        int n = nfirst + ln;
        int slo = start[n], shi = start[n + 1];
        int lo = max(slo, blo), hi = min(shi, bhi);
        float s = 0.f;
        for (int sl = lo; sl < hi; ++sl) s += stage[(sl - blo) * 17 + q];
        if (slo >= blo && shi <= bhi)
            marg_out[(size_t)n * Q + q] = s + field[(size_t)n * Q + q];
        else
            atomicAdd(marg_out + (size_t)n * Q + q, s);
    }
}

// final: per node log_softmax
__global__ __launch_bounds__(256) void node_out(
    const float* __restrict__ marg, float* __restrict__ out, int N)
{
    int i = blockIdx.x * 256 + threadIdx.x;
    if (i >= N) return;

    const float4* mp = (const float4*)(marg + (size_t)i * Q);
    float4 m0 = mp[0], m1 = mp[1], m2 = mp[2], m3 = mp[3];
    float x[Q] = {m0.x, m0.y, m0.z, m0.w, m1.x, m1.y, m1.z, m1.w,
                  m2.x, m2.y, m2.z, m2.w, m3.x, m3.y, m3.z, m3.w};

    float mx = x[0];
#pragma unroll
    for (int q = 1; q < Q; ++q) mx = fmaxf(mx, x[q]);
    float s = 0.f;
#pragma unroll
    for (int q = 0; q < Q; ++q) s += __expf(x[q] - mx);
    float lse = mx + __logf(s);

    float4* op = (float4*)(out + (size_t)i * Q);
    op[0] = make_float4(x[0]  - lse, x[1]  - lse, x[2]  - lse, x[3]  - lse);
    op[1] = make_float4(x[4]  - lse, x[5]  - lse, x[6]  - lse, x[7]  - lse);
    op[2] = make_float4(x[8]  - lse, x[9]  - lse, x[10] - lse, x[11] - lse);
    op[3] = make_float4(x[12] - lse, x[13] - lse, x[14] - lse, x[15] - lse);
}

extern "C" void kernel_launch(void* const* d_in, const int* in_sizes, int n_in,
                              void* d_out, int out_size, void* d_ws, size_t ws_size,
                              hipStream_t stream) {
    // inputs: 0 marg_i (dead), 1 cav_ij, 2 C, 3 field_i, 4 edge_dst, 5 a1_src, 6 indice_ij
    const float* cav_in   = (const float*)d_in[1];
    const float* C        = (const float*)d_in[2];
    const float* field_i  = (const float*)d_in[3];
    const int*   edge_dst = (const int*)d_in[4];
    const int*   a1_src   = (const int*)d_in[5];
    const int*   indice   = (const int*)d_in[6];
    float* out = (float*)d_out;

    const int E = in_sizes[4];
    const int N = in_sizes[0] / Q;

    char* ws = (char*)d_ws;
    const size_t t2_bytes   = (size_t)E * 32;            // fp16 rows, 32B each
    const size_t i4_bytes   = (size_t)E * 16;
    const size_t node_bytes = (size_t)N * Q * sizeof(float);
    u32*   t2a    = (u32*)ws;                     ws += t2_bytes;
    u32*   t2b    = (u32*)ws;                     ws += t2_bytes;
    int4*  zip    = (int4*)ws;                    ws += i4_bytes;
    int4*  sorted = (int4*)ws;                    ws += i4_bytes;
    int2*  meta2  = (int2*)ws;                    ws += (size_t)E * 8;
    float* marg_a = (float*)ws;                   ws += node_bytes;
    float* marg_b = (float*)ws;                   ws += node_bytes;
    int*   pos    = (int*)ws;                     ws += (size_t)E * 4;
    int*   count  = (int*)ws;                     ws += (size_t)N * 4;
    int*   start  = (int*)ws;                     ws += (size_t)(N + 1) * 4;
    int*   cursor = (int*)ws;

    const int eb = 256;
    const int eg = (E + eb - 1) / eb;
    const int ng = (N + eb - 1) / eb;

    // ---- one-time dst-sorted metadata build ----
    hipMemsetAsync(count, 0, (size_t)N * 4, stream);
    hist_kernel<<<eg, eb, 0, stream>>>(edge_dst, count, E);
    scan_kernel<<<1, 1024, 0, stream>>>(count, start, N);
    hipMemcpyAsync(cursor, start, (size_t)N * 4, hipMemcpyDeviceToDevice, stream);
    rank_kernel<<<eg, eb, 0, stream>>>(edge_dst, cursor, pos, E);
    compose_zip<<<eg, eb, 0, stream>>>(a1_src, indice, edge_dst, pos, zip, E);
    scatter4<<<eg, eb, 0, stream>>>(zip, pos, sorted, E);
    meta_pack<<<eg, eb, 0, stream>>>(sorted, meta2, E);

    // ---- DEPTH rounds, marg double-buffered ----
    u32* t_cur = t2a;
    u32* t_nxt = t2b;
    float* m_in = marg_b;
    float* m_out = marg_a;

    for (int it = 0; it < DEPTH; ++it) {
        hipMemcpyAsync(m_out, field_i, node_bytes, hipMemcpyDeviceToDevice, stream);
        if (it == 0)
            fused_round<0><<<eg, eb, 0, stream>>>(sorted, meta2, C, cav_in,
                                                  nullptr, nullptr, start, field_i,
                                                  t_cur, m_out, E);
        else if (it != DEPTH - 1)
            fused_round<1><<<eg, eb, 0, stream>>>(sorted, meta2, C, nullptr,
                                                  m_in, t_cur, start, field_i,
                                                  t_nxt, m_out, E);
        else
            fused_round<2><<<eg, eb, 0, stream>>>(sorted, meta2, C, nullptr,
                                                  m_in, t_cur, start, field_i,
                                                  nullptr, m_out, E);
        if (it != 0) { u32* tt = t_cur; t_cur = t_nxt; t_nxt = tt; }
        float* tm = m_in; m_in = m_out; m_out = tm;
    }

    node_out<<<ng, eb, 0, stream>>>(m_in, out, N);
}

// Round 8
// 666.511 us; speedup vs baseline: 10.5467x; 1.0982x over previous
//
#include <hip/hip_runtime.h>
#include <hip/hip_fp16.h>

#define Q 16
#define EPS 1e-8f
#define DEPTH 5

typedef unsigned int u32;
typedef _Float16 h2 __attribute__((ext_vector_type(2)));

__device__ __forceinline__ u32 pack2(float a, float b) {
    __half2 h = __floats2half2_rn(a, b);
    return *(u32*)&h;
}
__device__ __forceinline__ float2 unpack2(u32 u) {
    __half2 h = *(__half2*)&u;
    return __half22float2(h);
}
__device__ __forceinline__ h2 mkh2(float a, float b) {
    h2 v; v[0] = (_Float16)a; v[1] = (_Float16)b; return v;
}

// ---------- one-time build: dst-sorted slot metadata ----------

__global__ __launch_bounds__(256) void hist_kernel(
    const int* __restrict__ dst, int* __restrict__ count, int E)
{
    int e = blockIdx.x * 256 + threadIdx.x;
    if (e < E) atomicAdd(&count[dst[e]], 1);
}

// --- parallel exclusive scan: count[0..N) -> start[0..N] ---
__global__ __launch_bounds__(256) void scan_partial(
    const int* __restrict__ count, int* __restrict__ partial, int N)
{
    __shared__ int sm[256];
    int i = blockIdx.x * 256 + threadIdx.x;
    sm[threadIdx.x] = (i < N) ? count[i] : 0;
    __syncthreads();
    for (int off = 128; off > 0; off >>= 1) {
        if (threadIdx.x < off) sm[threadIdx.x] += sm[threadIdx.x + off];
        __syncthreads();
    }
    if (threadIdx.x == 0) partial[blockIdx.x] = sm[0];
}

__global__ __launch_bounds__(1024) void scan_top(
    int* __restrict__ partial, int nb)
{
    __shared__ int sm[1024];
    int t = threadIdx.x;
    int v = (t < nb) ? partial[t] : 0;
    sm[t] = v;
    __syncthreads();
    for (int off = 1; off < 1024; off <<= 1) {
        int u = (t >= off) ? sm[t - off] : 0;
        __syncthreads();
        sm[t] += u;
        __syncthreads();
    }
    if (t < nb) partial[t] = sm[t] - v;   // exclusive prefix of block sums
}

__global__ __launch_bounds__(256) void scan_final(
    const int* __restrict__ count, const int* __restrict__ partial,
    int* __restrict__ start, int N)
{
    __shared__ int sm[256];
    int i = blockIdx.x * 256 + threadIdx.x;
    int v = (i < N) ? count[i] : 0;
    sm[threadIdx.x] = v;
    __syncthreads();
    for (int off = 1; off < 256; off <<= 1) {
        int u = (threadIdx.x >= off) ? sm[threadIdx.x - off] : 0;
        __syncthreads();
        sm[threadIdx.x] += u;
        __syncthreads();
    }
    int excl = sm[threadIdx.x] - v + partial[blockIdx.x];
    if (i < N) start[i] = excl;
    if (i == N - 1) start[N] = excl + v;
}

__global__ __launch_bounds__(256) void rank_kernel(
    const int* __restrict__ dst, int* __restrict__ cursor,
    int* __restrict__ pos, int E)
{
    int e = blockIdx.x * 256 + threadIdx.x;
    if (e < E) pos[e] = atomicAdd(&cursor[dst[e]], 1);
}

// zip[e] = (a1_src[e], pos[indice[e]], dst[e], e)
__global__ __launch_bounds__(256) void compose_zip(
    const int* __restrict__ a1_src, const int* __restrict__ indice,
    const int* __restrict__ dst, const int* __restrict__ pos,
    int4* __restrict__ zip, int E)
{
    int e = blockIdx.x * 256 + threadIdx.x;
    if (e < E) zip[e] = make_int4(a1_src[e], pos[indice[e]], dst[e], e);
}

// sorted[pos[e]] = zip[e]   (single 16B scatter)
__global__ __launch_bounds__(256) void scatter4(
    const int4* __restrict__ zip, const int* __restrict__ pos,
    int4* __restrict__ sorted, int E)
{
    int e = blockIdx.x * 256 + threadIdx.x;
    if (e < E) sorted[pos[e]] = zip[e];
}

// meta2[j] = (ind2, dst<<16 | src)   — 8B/slot for rounds 2..DEPTH
__global__ __launch_bounds__(256) void meta_pack(
    const int4* __restrict__ sorted, int2* __restrict__ meta2, int E)
{
    int j = blockIdx.x * 256 + threadIdx.x;
    if (j < E) {
        int4 m = sorted[j];
        meta2[j] = make_int2(m.y, (m.z << 16) | m.x);
    }
}

// boundary nodes: slot range crosses a 256-slot window, or empty.
// Only these need marg pre-init (interior nodes are direct-written).
__global__ __launch_bounds__(256) void bnode_build(
    const int* __restrict__ start, int* __restrict__ blist,
    int* __restrict__ bcount, int N)
{
    int n = blockIdx.x * 256 + threadIdx.x;
    if (n >= N) return;
    int slo = start[n], shi = start[n + 1];
    bool need = (slo == shi) || ((slo >> 8) != ((shi - 1) >> 8));
    if (need) {
        int p = atomicAdd(bcount, 1);
        blist[p] = n;
    }
}

// per-round: init only boundary-node rows to field (4 threads/node, float4)
__global__ __launch_bounds__(256) void binit(
    const int* __restrict__ blist, const int* __restrict__ bcount,
    const float* __restrict__ field, float* __restrict__ marg)
{
    int idx = blockIdx.x * 256 + threadIdx.x;
    int cnt = *bcount;
    if (idx >= cnt * 4) return;
    int n = blist[idx >> 2], part = idx & 3;
    ((float4*)(marg + (size_t)n * Q))[part] =
        ((const float4*)(field + (size_t)n * Q))[part];
}

// ---------- fused per-round kernel ----------
// MODE 0: round 1 (reads cav via sorted.w), writes t2
// MODE 1: mid rounds (reads marg_in/t2_old via meta2), writes t2
// MODE 2: last round (as 1, skips dead t2 write)
// All: segment-reduce t rows into marg_out (boundary rows pre-init to field).
template<int MODE>
__global__ __launch_bounds__(256) void fused_round(
    const int4* __restrict__ sorted, const int2* __restrict__ meta2,
    const float* __restrict__ C,
    const float* __restrict__ cav,
    const float* __restrict__ marg_in, const u32* __restrict__ t2_old,
    const int* __restrict__ start, const float* __restrict__ field,
    u32* __restrict__ t2_new, float* __restrict__ marg_out, int E)
{
    __shared__ __align__(16) h2 Csh[Q * 8];   // column-major fp16
    __shared__ float stage[256 * 17];
    __shared__ int s_nfirst, s_nlast;

    const int tid = threadIdx.x;
    const int blo = blockIdx.x * 256;
    const int bhi = min(blo + 256, E);
    if (tid < 128) {
        int q = tid >> 3, kk = tid & 7;
        Csh[q * 8 + kk] = mkh2(C[(2 * kk) * Q + q], C[(2 * kk + 1) * Q + q]);
    }
    if (tid == 0) {
        if (MODE == 0) {
            s_nfirst = sorted[blo].z;
            s_nlast  = sorted[bhi - 1].z;
        } else {
            s_nfirst = ((u32)meta2[blo].y) >> 16;
            s_nlast  = ((u32)meta2[bhi - 1].y) >> 16;
        }
    }
    __syncthreads();

    const int j = blo + tid;
    float t[Q];
    if (j < E) {
        h2 uh[8];
        float s, logs;
        if (MODE == 0) {
            const int e = sorted[j].w;
            const float4* rp = (const float4*)(cav + (size_t)e * Q);
            float4 a0 = rp[0], a1 = rp[1], a2 = rp[2], a3 = rp[3];
            uh[0] = mkh2(a0.x, a0.y); uh[1] = mkh2(a0.z, a0.w);
            uh[2] = mkh2(a1.x, a1.y); uh[3] = mkh2(a1.z, a1.w);
            uh[4] = mkh2(a2.x, a2.y); uh[5] = mkh2(a2.z, a2.w);
            uh[6] = mkh2(a3.x, a3.y); uh[7] = mkh2(a3.z, a3.w);
            s = 1.f; logs = 0.f;
        } else {
            const int2 meta = meta2[j];
            const int src = meta.y & 0xffff;
            const float4* mp = (const float4*)(marg_in + (size_t)src * Q);
            const uint4*  tp = (const uint4*)(t2_old + (size_t)meta.x * 8);
            float4 m0 = mp[0], m1 = mp[1], m2 = mp[2], m3 = mp[3];
            uint4 r0 = tp[0], r1 = tp[1];
            float2 p0 = unpack2(r0.x), p1 = unpack2(r0.y),
                   p2 = unpack2(r0.z), p3 = unpack2(r0.w);
            float2 p4 = unpack2(r1.x), p5 = unpack2(r1.y),
                   p6 = unpack2(r1.z), p7 = unpack2(r1.w);

            float x[Q] = {m0.x - p0.x, m0.y - p0.y, m0.z - p1.x, m0.w - p1.y,
                          m1.x - p2.x, m1.y - p2.y, m1.z - p3.x, m1.w - p3.y,
                          m2.x - p4.x, m2.y - p4.y, m2.z - p5.x, m2.w - p5.y,
                          m3.x - p6.x, m3.y - p6.y, m3.z - p7.x, m3.w - p7.y};

            float mx = x[0];
#pragma unroll
            for (int q = 1; q < Q; ++q) mx = fmaxf(mx, x[q]);
            float u[Q];
            s = 0.f;
#pragma unroll
            for (int q = 0; q < Q; ++q) { u[q] = __expf(x[q] - mx); s += u[q]; }
            logs = __logf(s);
#pragma unroll
            for (int k = 0; k < 8; ++k) uh[k] = mkh2(u[2 * k], u[2 * k + 1]);
        }

        const float base = EPS * s;
#pragma unroll
        for (int q = 0; q < Q; ++q) {
            const uint4* cp = (const uint4*)&Csh[q * 8];
            h2 col[8];
            ((uint4*)col)[0] = cp[0];
            ((uint4*)col)[1] = cp[1];
            float acc = base;
#pragma unroll
            for (int kk = 0; kk < 8; ++kk)
                acc = __builtin_amdgcn_fdot2(uh[kk], col[kk], acc, false);
            t[q] = __logf(acc) - logs;
        }

        if (MODE != 2) {
            uint4 w0, w1;
            w0.x = pack2(t[0],  t[1]);  w0.y = pack2(t[2],  t[3]);
            w0.z = pack2(t[4],  t[5]);  w0.w = pack2(t[6],  t[7]);
            w1.x = pack2(t[8],  t[9]);  w1.y = pack2(t[10], t[11]);
            w1.z = pack2(t[12], t[13]); w1.w = pack2(t[14], t[15]);
            uint4* op = (uint4*)(t2_new + (size_t)j * 8);   // coalesced stream
            op[0] = w0; op[1] = w1;
        }
    } else {
#pragma unroll
        for (int q = 0; q < Q; ++q) t[q] = 0.f;
    }

#pragma unroll
    for (int q = 0; q < Q; ++q) stage[tid * 17 + q] = t[q];
    __syncthreads();

    const int nfirst = s_nfirst;
    const int ncnt = s_nlast - nfirst + 1;
    for (int k = tid; k < ncnt * Q; k += 256) {
        int ln = k >> 4, q = k & 15;
        int n = nfirst + ln;
        int slo = start[n], shi = start[n + 1];
        int lo = max(slo, blo), hi = min(shi, bhi);
        float s = 0.f;
        for (int sl = lo; sl < hi; ++sl) s += stage[(sl - blo) * 17 + q];
        if (slo >= blo && shi <= bhi)
            marg_out[(size_t)n * Q + q] = s + field[(size_t)n * Q + q];
        else
            atomicAdd(marg_out + (size_t)n * Q + q, s);
    }
}

// final: per node log_softmax
__global__ __launch_bounds__(256) void node_out(
    const float* __restrict__ marg, float* __restrict__ out, int N)
{
    int i = blockIdx.x * 256 + threadIdx.x;
    if (i >= N) return;

    const float4* mp = (const float4*)(marg + (size_t)i * Q);
    float4 m0 = mp[0], m1 = mp[1], m2 = mp[2], m3 = mp[3];
    float x[Q] = {m0.x, m0.y, m0.z, m0.w, m1.x, m1.y, m1.z, m1.w,
                  m2.x, m2.y, m2.z, m2.w, m3.x, m3.y, m3.z, m3.w};

    float mx = x[0];
#pragma unroll
    for (int q = 1; q < Q; ++q) mx = fmaxf(mx, x[q]);
    float s = 0.f;
#pragma unroll
    for (int q = 0; q < Q; ++q) s += __expf(x[q] - mx);
    float lse = mx + __logf(s);

    float4* op = (float4*)(out + (size_t)i * Q);
    op[0] = make_float4(x[0]  - lse, x[1]  - lse, x[2]  - lse, x[3]  - lse);
    op[1] = make_float4(x[4]  - lse, x[5]  - lse, x[6]  - lse, x[7]  - lse);
    op[2] = make_float4(x[8]  - lse, x[9]  - lse, x[10] - lse, x[11] - lse);
    op[3] = make_float4(x[12] - lse, x[13] - lse, x[14] - lse, x[15] - lse);
}

extern "C" void kernel_launch(void* const* d_in, const int* in_sizes, int n_in,
                              void* d_out, int out_size, void* d_ws, size_t ws_size,
                              hipStream_t stream) {
    // inputs: 0 marg_i (dead), 1 cav_ij, 2 C, 3 field_i, 4 edge_dst, 5 a1_src, 6 indice_ij
    const float* cav_in   = (const float*)d_in[1];
    const float* C        = (const float*)d_in[2];
    const float* field_i  = (const float*)d_in[3];
    const int*   edge_dst = (const int*)d_in[4];
    const int*   a1_src   = (const int*)d_in[5];
    const int*   indice   = (const int*)d_in[6];
    float* out = (float*)d_out;

    const int E = in_sizes[4];
    const int N = in_sizes[0] / Q;

    char* ws = (char*)d_ws;
    const size_t t2_bytes   = (size_t)E * 32;            // fp16 rows, 32B each
    const size_t i4_bytes   = (size_t)E * 16;
    const size_t node_bytes = (size_t)N * Q * sizeof(float);
    u32*   t2a    = (u32*)ws;                     ws += t2_bytes;
    u32*   t2b    = (u32*)ws;                     ws += t2_bytes;
    int4*  zip    = (int4*)ws;                    ws += i4_bytes;
    int4*  sorted = (int4*)ws;                    ws += i4_bytes;
    int2*  meta2  = (int2*)ws;                    ws += (size_t)E * 8;
    float* marg_a = (float*)ws;                   ws += node_bytes;
    float* marg_b = (float*)ws;                   ws += node_bytes;
    int*   pos    = (int*)ws;                     ws += (size_t)E * 4;
    int*   count  = (int*)ws;                     ws += (size_t)N * 4;
    int*   bcount = (int*)ws;                     ws += 4;
    int*   start  = (int*)ws;                     ws += (size_t)(N + 1) * 4;
    int*   cursor = (int*)ws;                     ws += (size_t)N * 4;
    int*   blist  = (int*)ws;                     ws += (size_t)N * 4;
    int*   partial= (int*)ws;

    const int eb = 256;
    const int eg = (E + eb - 1) / eb;
    const int ng = (N + eb - 1) / eb;   // also = #scan blocks (<=1024 required)

    // ---- one-time dst-sorted metadata build ----
    hipMemsetAsync(count, 0, (size_t)N * 4 + 4, stream);   // count + bcount
    hist_kernel<<<eg, eb, 0, stream>>>(edge_dst, count, E);
    scan_partial<<<ng, eb, 0, stream>>>(count, partial, N);
    scan_top<<<1, 1024, 0, stream>>>(partial, ng);
    scan_final<<<ng, eb, 0, stream>>>(count, partial, start, N);
    hipMemcpyAsync(cursor, start, (size_t)N * 4, hipMemcpyDeviceToDevice, stream);
    rank_kernel<<<eg, eb, 0, stream>>>(edge_dst, cursor, pos, E);
    compose_zip<<<eg, eb, 0, stream>>>(a1_src, indice, edge_dst, pos, zip, E);
    scatter4<<<eg, eb, 0, stream>>>(zip, pos, sorted, E);
    meta_pack<<<eg, eb, 0, stream>>>(sorted, meta2, E);
    bnode_build<<<ng, eb, 0, stream>>>(start, blist, bcount, N);

    // ---- DEPTH rounds, marg double-buffered ----
    u32* t_cur = t2a;
    u32* t_nxt = t2b;
    float* m_in = marg_b;
    float* m_out = marg_a;
    const int bg = (N * 4 + eb - 1) / eb;   // binit worst-case grid, guarded

    for (int it = 0; it < DEPTH; ++it) {
        binit<<<bg, eb, 0, stream>>>(blist, bcount, field_i, m_out);
        if (it == 0)
            fused_round<0><<<eg, eb, 0, stream>>>(sorted, meta2, C, cav_in,
                                                  nullptr, nullptr, start, field_i,
                                                  t_cur, m_out, E);
        else if (it != DEPTH - 1)
            fused_round<1><<<eg, eb, 0, stream>>>(sorted, meta2, C, nullptr,
                                                  m_in, t_cur, start, field_i,
                                                  t_nxt, m_out, E);
        else
            fused_round<2><<<eg, eb, 0, stream>>>(sorted, meta2, C, nullptr,
                                                  m_in, t_cur, start, field_i,
                                                  nullptr, m_out, E);
        if (it != 0) { u32* tt = t_cur; t_cur = t_nxt; t_nxt = tt; }
        float* tm = m_in; m_in = m_out; m_out = tm;
    }

    node_out<<<ng, eb, 0, stream>>>(m_in, out, N);
}

// Round 9
// 608.072 us; speedup vs baseline: 11.5603x; 1.0961x over previous
//
#include <hip/hip_runtime.h>
#include <hip/hip_fp16.h>

#define Q 16
#define EPS 1e-8f
#define DEPTH 5

typedef unsigned int u32;
typedef _Float16 h2 __attribute__((ext_vector_type(2)));

__device__ __forceinline__ u32 pack2(float a, float b) {
    __half2 h = __floats2half2_rn(a, b);
    return *(u32*)&h;
}
__device__ __forceinline__ float2 unpack2(u32 u) {
    __half2 h = *(__half2*)&u;
    return __half22float2(h);
}
__device__ __forceinline__ h2 mkh2(float a, float b) {
    h2 v; v[0] = (_Float16)a; v[1] = (_Float16)b; return v;
}

// ---------- one-time build: dst-sorted slot metadata ----------

// Single atomic pass: lr[e] = local rank of e within its dst; count[n] ends
// as degree(n). (Replaces separate hist + rank passes.)
__global__ __launch_bounds__(256) void rank0_kernel(
    const int* __restrict__ dst, int* __restrict__ count,
    int* __restrict__ lr, int E)
{
    int e = blockIdx.x * 256 + threadIdx.x;
    if (e < E) lr[e] = atomicAdd(&count[dst[e]], 1);
}

// --- parallel exclusive scan: count[0..N) -> start[0..N] ---
__global__ __launch_bounds__(256) void scan_partial(
    const int* __restrict__ count, int* __restrict__ partial, int N)
{
    __shared__ int sm[256];
    int i = blockIdx.x * 256 + threadIdx.x;
    sm[threadIdx.x] = (i < N) ? count[i] : 0;
    __syncthreads();
    for (int off = 128; off > 0; off >>= 1) {
        if (threadIdx.x < off) sm[threadIdx.x] += sm[threadIdx.x + off];
        __syncthreads();
    }
    if (threadIdx.x == 0) partial[blockIdx.x] = sm[0];
}

__global__ __launch_bounds__(1024) void scan_top(
    int* __restrict__ partial, int nb)
{
    __shared__ int sm[1024];
    int t = threadIdx.x;
    int v = (t < nb) ? partial[t] : 0;
    sm[t] = v;
    __syncthreads();
    for (int off = 1; off < 1024; off <<= 1) {
        int u = (t >= off) ? sm[t - off] : 0;
        __syncthreads();
        sm[t] += u;
        __syncthreads();
    }
    if (t < nb) partial[t] = sm[t] - v;
}

__global__ __launch_bounds__(256) void scan_final(
    const int* __restrict__ count, const int* __restrict__ partial,
    int* __restrict__ start, int N)
{
    __shared__ int sm[256];
    int i = blockIdx.x * 256 + threadIdx.x;
    int v = (i < N) ? count[i] : 0;
    sm[threadIdx.x] = v;
    __syncthreads();
    for (int off = 1; off < 256; off <<= 1) {
        int u = (threadIdx.x >= off) ? sm[threadIdx.x - off] : 0;
        __syncthreads();
        sm[threadIdx.x] += u;
        __syncthreads();
    }
    int excl = sm[threadIdx.x] - v + partial[blockIdx.x];
    if (i < N) start[i] = excl;
    if (i == N - 1) start[N] = excl + v;
}

// pos[e] = start[dst[e]] + lr[e]
__global__ __launch_bounds__(256) void pos_kernel(
    const int* __restrict__ dst, const int* __restrict__ lr,
    const int* __restrict__ start, int* __restrict__ pos, int E)
{
    int e = blockIdx.x * 256 + threadIdx.x;
    if (e < E) pos[e] = start[dst[e]] + lr[e];
}

// sorted[pos[e]] = (a1_src[e], pos[indice[e]], dst[e], e)  — one 16B scatter
__global__ __launch_bounds__(256) void scatter_direct(
    const int* __restrict__ a1_src, const int* __restrict__ indice,
    const int* __restrict__ dst, const int* __restrict__ pos,
    int4* __restrict__ sorted, int E)
{
    int e = blockIdx.x * 256 + threadIdx.x;
    if (e < E)
        sorted[pos[e]] = make_int4(a1_src[e], pos[indice[e]], dst[e], e);
}

// meta2[j] = (ind2, dst<<16 | src)   — 8B/slot for rounds 2..DEPTH
__global__ __launch_bounds__(256) void meta_pack(
    const int4* __restrict__ sorted, int2* __restrict__ meta2, int E)
{
    int j = blockIdx.x * 256 + threadIdx.x;
    if (j < E) {
        int4 m = sorted[j];
        meta2[j] = make_int2(m.y, (m.z << 16) | m.x);
    }
}

// boundary nodes: slot range crosses a 256-slot window, or empty.
__global__ __launch_bounds__(256) void bnode_build(
    const int* __restrict__ start, int* __restrict__ blist,
    int* __restrict__ bcount, int N)
{
    int n = blockIdx.x * 256 + threadIdx.x;
    if (n >= N) return;
    int slo = start[n], shi = start[n + 1];
    bool need = (slo == shi) || ((slo >> 8) != ((shi - 1) >> 8));
    if (need) {
        int p = atomicAdd(bcount, 1);
        blist[p] = n;
    }
}

// per-round: init only boundary-node rows to field
__global__ __launch_bounds__(256) void binit(
    const int* __restrict__ blist, const int* __restrict__ bcount,
    const float* __restrict__ field, float* __restrict__ marg)
{
    int idx = blockIdx.x * 256 + threadIdx.x;
    int cnt = *bcount;
    if (idx >= cnt * 4) return;
    int n = blist[idx >> 2], part = idx & 3;
    ((float4*)(marg + (size_t)n * Q))[part] =
        ((const float4*)(field + (size_t)n * Q))[part];
}

// ---------- fused per-round kernel ----------
// MODE 0: round 1 (reads cav via sorted.w), writes t2
// MODE 1: mid rounds (reads marg_in/t2_old via meta2), writes t2
// MODE 2: last round (as 1, skips dead t2 write)
template<int MODE>
__global__ __launch_bounds__(256) void fused_round(
    const int4* __restrict__ sorted, const int2* __restrict__ meta2,
    const float* __restrict__ C,
    const float* __restrict__ cav,
    const float* __restrict__ marg_in, const u32* __restrict__ t2_old,
    const int* __restrict__ start, const float* __restrict__ field,
    u32* __restrict__ t2_new, float* __restrict__ marg_out, int E)
{
    __shared__ __align__(16) h2 Csh[Q * 8];   // column-major fp16
    __shared__ float stage[256 * 17];
    __shared__ int s_nfirst, s_nlast;

    const int tid = threadIdx.x;
    const int blo = blockIdx.x * 256;
    const int bhi = min(blo + 256, E);
    const int j = blo + tid;
    const bool act = (j < E);

    // ---- issue ALL global loads first (overlap latency with LDS staging) ----
    int4 smeta;
    int2 meta;
    float4 m0, m1, m2, m3;
    uint4 r0, r1;
    if (MODE == 0) {
        if (act) {
            smeta = sorted[j];
            const float4* rp = (const float4*)(cav + (size_t)smeta.w * Q);
            m0 = rp[0]; m1 = rp[1]; m2 = rp[2]; m3 = rp[3];
        }
    } else {
        if (act) {
            meta = meta2[j];
            const int src = meta.y & 0xffff;
            const float4* mp = (const float4*)(marg_in + (size_t)src * Q);
            const uint4*  tp = (const uint4*)(t2_old + (size_t)meta.x * 8);
            m0 = mp[0]; m1 = mp[1]; m2 = mp[2]; m3 = mp[3];
            r0 = tp[0]; r1 = tp[1];
        }
    }

    if (tid < 128) {
        int q = tid >> 3, kk = tid & 7;
        Csh[q * 8 + kk] = mkh2(C[(2 * kk) * Q + q], C[(2 * kk + 1) * Q + q]);
    }
    if (act) {
        int mydst = (MODE == 0) ? smeta.z : (int)(((u32)meta.y) >> 16);
        if (j == blo)     s_nfirst = mydst;
        if (j == bhi - 1) s_nlast  = mydst;
    }
    __syncthreads();

    float t[Q];
    if (act) {
        h2 uh[8];
        float s, logs;
        if (MODE == 0) {
            uh[0] = mkh2(m0.x, m0.y); uh[1] = mkh2(m0.z, m0.w);
            uh[2] = mkh2(m1.x, m1.y); uh[3] = mkh2(m1.z, m1.w);
            uh[4] = mkh2(m2.x, m2.y); uh[5] = mkh2(m2.z, m2.w);
            uh[6] = mkh2(m3.x, m3.y); uh[7] = mkh2(m3.z, m3.w);
            s = 1.f; logs = 0.f;
        } else {
            float2 p0 = unpack2(r0.x), p1 = unpack2(r0.y),
                   p2 = unpack2(r0.z), p3 = unpack2(r0.w);
            float2 p4 = unpack2(r1.x), p5 = unpack2(r1.y),
                   p6 = unpack2(r1.z), p7 = unpack2(r1.w);

            float x[Q] = {m0.x - p0.x, m0.y - p0.y, m0.z - p1.x, m0.w - p1.y,
                          m1.x - p2.x, m1.y - p2.y, m1.z - p3.x, m1.w - p3.y,
                          m2.x - p4.x, m2.y - p4.y, m2.z - p5.x, m2.w - p5.y,
                          m3.x - p6.x, m3.y - p6.y, m3.z - p7.x, m3.w - p7.y};

            float mx = x[0];
#pragma unroll
            for (int q = 1; q < Q; ++q) mx = fmaxf(mx, x[q]);
            float u[Q];
            s = 0.f;
#pragma unroll
            for (int q = 0; q < Q; ++q) { u[q] = __expf(x[q] - mx); s += u[q]; }
            logs = __logf(s);
#pragma unroll
            for (int k = 0; k < 8; ++k) uh[k] = mkh2(u[2 * k], u[2 * k + 1]);
        }

        const float base = EPS * s;
#pragma unroll
        for (int q = 0; q < Q; ++q) {
            const uint4* cp = (const uint4*)&Csh[q * 8];
            h2 col[8];
            ((uint4*)col)[0] = cp[0];
            ((uint4*)col)[1] = cp[1];
            float acc = base;
#pragma unroll
            for (int kk = 0; kk < 8; ++kk)
                acc = __builtin_amdgcn_fdot2(uh[kk], col[kk], acc, false);
            t[q] = __logf(acc) - logs;
        }

        if (MODE != 2) {
            uint4 w0, w1;
            w0.x = pack2(t[0],  t[1]);  w0.y = pack2(t[2],  t[3]);
            w0.z = pack2(t[4],  t[5]);  w0.w = pack2(t[6],  t[7]);
            w1.x = pack2(t[8],  t[9]);  w1.y = pack2(t[10], t[11]);
            w1.z = pack2(t[12], t[13]); w1.w = pack2(t[14], t[15]);
            uint4* op = (uint4*)(t2_new + (size_t)j * 8);   // coalesced stream
            op[0] = w0; op[1] = w1;
        }
    } else {
#pragma unroll
        for (int q = 0; q < Q; ++q) t[q] = 0.f;
    }

#pragma unroll
    for (int q = 0; q < Q; ++q) stage[tid * 17 + q] = t[q];
    __syncthreads();

    const int nfirst = s_nfirst;
    const int ncnt = s_nlast - nfirst + 1;
    for (int k = tid; k < ncnt * Q; k += 256) {
        int ln = k >> 4, q = k & 15;
        int n = nfirst + ln;
        int slo = start[n], shi = start[n + 1];
        int lo = max(slo, blo), hi = min(shi, bhi);
        float s = 0.f;
        for (int sl = lo; sl < hi; ++sl) s += stage[(sl - blo) * 17 + q];
        if (slo >= blo && shi <= bhi)
            marg_out[(size_t)n * Q + q] = s + field[(size_t)n * Q + q];
        else
            atomicAdd(marg_out + (size_t)n * Q + q, s);
    }
}

// final: per node log_softmax
__global__ __launch_bounds__(256) void node_out(
    const float* __restrict__ marg, float* __restrict__ out, int N)
{
    int i = blockIdx.x * 256 + threadIdx.x;
    if (i >= N) return;

    const float4* mp = (const float4*)(marg + (size_t)i * Q);
    float4 m0 = mp[0], m1 = mp[1], m2 = mp[2], m3 = mp[3];
    float x[Q] = {m0.x, m0.y, m0.z, m0.w, m1.x, m1.y, m1.z, m1.w,
                  m2.x, m2.y, m2.z, m2.w, m3.x, m3.y, m3.z, m3.w};

    float mx = x[0];
#pragma unroll
    for (int q = 1; q < Q; ++q) mx = fmaxf(mx, x[q]);
    float s = 0.f;
#pragma unroll
    for (int q = 0; q < Q; ++q) s += __expf(x[q] - mx);
    float lse = mx + __logf(s);

    float4* op = (float4*)(out + (size_t)i * Q);
    op[0] = make_float4(x[0]  - lse, x[1]  - lse, x[2]  - lse, x[3]  - lse);
    op[1] = make_float4(x[4]  - lse, x[5]  - lse, x[6]  - lse, x[7]  - lse);
    op[2] = make_float4(x[8]  - lse, x[9]  - lse, x[10] - lse, x[11] - lse);
    op[3] = make_float4(x[12] - lse, x[13] - lse, x[14] - lse, x[15] - lse);
}

extern "C" void kernel_launch(void* const* d_in, const int* in_sizes, int n_in,
                              void* d_out, int out_size, void* d_ws, size_t ws_size,
                              hipStream_t stream) {
    // inputs: 0 marg_i (dead), 1 cav_ij, 2 C, 3 field_i, 4 edge_dst, 5 a1_src, 6 indice_ij
    const float* cav_in   = (const float*)d_in[1];
    const float* C        = (const float*)d_in[2];
    const float* field_i  = (const float*)d_in[3];
    const int*   edge_dst = (const int*)d_in[4];
    const int*   a1_src   = (const int*)d_in[5];
    const int*   indice   = (const int*)d_in[6];
    float* out = (float*)d_out;

    const int E = in_sizes[4];
    const int N = in_sizes[0] / Q;

    char* ws = (char*)d_ws;
    const size_t t2_bytes   = (size_t)E * 32;            // fp16 rows, 32B each
    const size_t i4_bytes   = (size_t)E * 16;
    const size_t node_bytes = (size_t)N * Q * sizeof(float);
    u32*   t2a    = (u32*)ws;                     ws += t2_bytes;
    u32*   t2b    = (u32*)ws;                     ws += t2_bytes;
    int4*  sorted = (int4*)ws;                    ws += i4_bytes;
    int2*  meta2  = (int2*)ws;                    ws += (size_t)E * 8;
    float* marg_a = (float*)ws;                   ws += node_bytes;
    float* marg_b = (float*)ws;                   ws += node_bytes;
    int*   pos    = (int*)ws;                     ws += (size_t)E * 4;
    int*   lr     = (int*)ws;                     ws += (size_t)E * 4;
    int*   count  = (int*)ws;                     ws += (size_t)N * 4;
    int*   bcount = (int*)ws;                     ws += 4;
    int*   start  = (int*)ws;                     ws += (size_t)(N + 1) * 4;
    int*   blist  = (int*)ws;                     ws += (size_t)N * 4;
    int*   partial= (int*)ws;

    const int eb = 256;
    const int eg = (E + eb - 1) / eb;
    const int ng = (N + eb - 1) / eb;   // #scan blocks (<=1024 required)

    // ---- one-time dst-sorted metadata build ----
    hipMemsetAsync(count, 0, (size_t)N * 4 + 4, stream);   // count + bcount
    rank0_kernel<<<eg, eb, 0, stream>>>(edge_dst, count, lr, E);
    scan_partial<<<ng, eb, 0, stream>>>(count, partial, N);
    scan_top<<<1, 1024, 0, stream>>>(partial, ng);
    scan_final<<<ng, eb, 0, stream>>>(count, partial, start, N);
    pos_kernel<<<eg, eb, 0, stream>>>(edge_dst, lr, start, pos, E);
    scatter_direct<<<eg, eb, 0, stream>>>(a1_src, indice, edge_dst, pos, sorted, E);
    meta_pack<<<eg, eb, 0, stream>>>(sorted, meta2, E);
    bnode_build<<<ng, eb, 0, stream>>>(start, blist, bcount, N);

    // ---- DEPTH rounds, marg double-buffered ----
    u32* t_cur = t2a;
    u32* t_nxt = t2b;
    float* m_in = marg_b;
    float* m_out = marg_a;
    const int bg = (N * 4 + eb - 1) / eb;

    for (int it = 0; it < DEPTH; ++it) {
        binit<<<bg, eb, 0, stream>>>(blist, bcount, field_i, m_out);
        if (it == 0)
            fused_round<0><<<eg, eb, 0, stream>>>(sorted, meta2, C, cav_in,
                                                  nullptr, nullptr, start, field_i,
                                                  t_cur, m_out, E);
        else if (it != DEPTH - 1)
            fused_round<1><<<eg, eb, 0, stream>>>(sorted, meta2, C, nullptr,
                                                  m_in, t_cur, start, field_i,
                                                  t_nxt, m_out, E);
        else
            fused_round<2><<<eg, eb, 0, stream>>>(sorted, meta2, C, nullptr,
                                                  m_in, t_cur, start, field_i,
                                                  nullptr, m_out, E);
        if (it != 0) { u32* tt = t_cur; t_cur = t_nxt; t_nxt = tt; }
        float* tm = m_in; m_in = m_out; m_out = tm;
    }

    node_out<<<ng, eb, 0, stream>>>(m_in, out, N);
}